// Round 13
// baseline (406.673 us; speedup 1.0000x reference)
//
#include <hip/hip_runtime.h>
#include <math.h>

typedef __bf16 bf16x8 __attribute__((ext_vector_type(8)));
typedef float  f32x4  __attribute__((ext_vector_type(4)));
typedef float  f32x2  __attribute__((ext_vector_type(2)));
typedef unsigned short ushort_t;
typedef unsigned short ushort8 __attribute__((ext_vector_type(8)));

// Problem constants (fixed by the reference).
constexpr int Nn = 50000;   // nodes
constexpr int Ee = 800000;  // edges
constexpr int Dd = 128;     // feature dim
constexpr int Gg = 64;      // graphs
constexpr float SCALE = 0.08838834764831845f; // 1/sqrt(128)

__device__ inline ushort_t f2bf(float f) {
    unsigned u = __float_as_uint(f);
    unsigned r = (u + 0x7FFF + ((u >> 16) & 1)) >> 16;   // RNE truncate to bf16
    return (ushort_t)r;
}
__device__ inline float bf2f(ushort_t b) { return __uint_as_float(((unsigned)b) << 16); }

// 4 packed fp8 (e4m3) -> 4 floats via HW packed converts
__device__ inline void fp8x4_to_f32(int w, float* out) {
    f32x2 lo = __builtin_amdgcn_cvt_pk_f32_fp8(w, false);
    f32x2 hi = __builtin_amdgcn_cvt_pk_f32_fp8(w, true);
    out[0] = lo[0]; out[1] = lo[1]; out[2] = hi[0]; out[3] = hi[1];
}

// ---------------- CSR build (sort edges by dst) + graph bounds ----------------

constexpr int EB  = (Ee + 255) / 256;   // 3125 hist blocks
constexpr int NBD = (Nn + 255) / 256;   // 196 bound blocks

__global__ __launch_bounds__(256) void hist_bound_kernel(const int* __restrict__ dst,
                                                         int* __restrict__ counts,
                                                         const int* __restrict__ batch,
                                                         int* __restrict__ startg,
                                                         int* __restrict__ endg) {
    int b = blockIdx.x;
    if (b < EB) {
        int e = b * 256 + threadIdx.x;
        if (e < Ee) atomicAdd(&counts[dst[e]], 1);
    } else {
        int n = (b - EB) * 256 + threadIdx.x;
        if (n >= Nn) return;
        int g = batch[n];
        if (n == Nn - 1 || batch[n + 1] != g) endg[g] = n + 1;
        if (n == 0 || batch[n - 1] != g) startg[g] = n;
    }
}

__global__ __launch_bounds__(256) void scan1_kernel(const int* __restrict__ counts,
                                                    int* __restrict__ offsets,
                                                    int* __restrict__ blockSums) {
    __shared__ int sh[256];
    int i = blockIdx.x * 256 + threadIdx.x;
    int v = (i < Nn) ? counts[i] : 0;
    sh[threadIdx.x] = v;
    __syncthreads();
    for (int off = 1; off < 256; off <<= 1) {
        int t = (threadIdx.x >= off) ? sh[threadIdx.x - off] : 0;
        __syncthreads();
        sh[threadIdx.x] += t;
        __syncthreads();
    }
    if (i < Nn) offsets[i] = sh[threadIdx.x] - v;   // exclusive within block
    if (threadIdx.x == 255) blockSums[blockIdx.x] = sh[255];
}

__global__ __launch_bounds__(256) void scan2_kernel(int* __restrict__ blockSums, int nb) {
    __shared__ int sh[256];
    int t = threadIdx.x;
    int v = (t < nb) ? blockSums[t] : 0;
    sh[t] = v;
    __syncthreads();
    for (int off = 1; off < 256; off <<= 1) {
        int u = (t >= off) ? sh[t - off] : 0;
        __syncthreads();
        sh[t] += u;
        __syncthreads();
    }
    if (t < nb) blockSums[t] = sh[t] - v;           // exclusive across blocks
}

__global__ __launch_bounds__(256) void scan3_kernel(int* __restrict__ offsets,
                                                    const int* __restrict__ blockSums,
                                                    int* __restrict__ cursor) {
    int i = blockIdx.x * 256 + threadIdx.x;
    if (i < Nn) {
        int o = offsets[i] + blockSums[blockIdx.x];
        offsets[i] = o;
        cursor[i] = o;
    }
    if (i == 0) offsets[Nn] = Ee;
}

__global__ __launch_bounds__(256) void scatter_kernel(const int* __restrict__ src,
                                                      const int* __restrict__ dst,
                                                      int* __restrict__ cursor,
                                                      int* __restrict__ sorted_src) {
    int e = blockIdx.x * 256 + threadIdx.x;
    if (e < Ee) {
        int d = dst[e];
        int pos = atomicAdd(&cursor[d], 1);
        sorted_src[pos] = src[e];
    }
}

// ---------------- split-bf16 conversion ----------------

__global__ __launch_bounds__(256) void convx_kernel(const float* __restrict__ X,
                                                    ushort_t* __restrict__ Xh,
                                                    ushort_t* __restrict__ Xl,
                                                    int n4) {
    int i = blockIdx.x * 256 + threadIdx.x;
    if (i >= n4) return;
    float4 x = ((const float4*)X)[i];
    ushort4 h, l;
    h.x = f2bf(x.x); l.x = f2bf(x.x - bf2f(h.x));
    h.y = f2bf(x.y); l.y = f2bf(x.y - bf2f(h.y));
    h.z = f2bf(x.z); l.z = f2bf(x.z - bf2f(h.z));
    h.w = f2bf(x.w); l.w = f2bf(x.w - bf2f(h.w));
    ((ushort4*)Xh)[i] = h;
    ((ushort4*)Xl)[i] = l;
}

// Fragment-order split-bf16 weights: wave's weight fragment load is a
// contiguous 1KB (coalesced) — R9's request-rate fix.
__global__ __launch_bounds__(256) void convw_kernel(
    const float* w0, const float* w1, const float* w2, const float* w3,
    const float* w4, const float* w5, const float* w6, const float* w7,
    ushort_t* __restrict__ Wfh, ushort_t* __restrict__ Wfl) {
    const float* ws[8] = {w0, w1, w2, w3, w4, w5, w6, w7};
    int m = blockIdx.x >> 3;                       // 8 blocks per matrix
    int tt = (blockIdx.x & 7) * 256 + threadIdx.x; // 0..2047 fragment slots
    int wv = tt >> 9, ct = (tt >> 8) & 1, kc = (tt >> 6) & 3, lane = tt & 63;
    int ln = lane & 15, quad = lane >> 4;
    int n = wv * 32 + ct * 16 + ln;
    int k0 = kc * 32 + quad * 8;
    const float* srcp = ws[m] + n * 128 + k0;
    float4 a = *(const float4*)(srcp);
    float4 b = *(const float4*)(srcp + 4);
    float e[8] = {a.x, a.y, a.z, a.w, b.x, b.y, b.z, b.w};
    ushort8 h, l;
#pragma unroll
    for (int j = 0; j < 8; ++j) {
        h[j] = f2bf(e[j]);
        l[j] = f2bf(e[j] - bf2f(h[j]));
    }
    size_t o = (size_t)m * 16384 + (size_t)tt * 8;
    *(ushort8*)(Wfh + o) = h;
    *(ushort8*)(Wfl + o) = l;
}

// ---------------- MFMA split-bf16 GEMM: Y = X @ W^T + b ----------------
// LDS-staged X (coalesced 4KB loads), fragment-order weights.
// q,s out bf16; k,v out FP8-e4m3, interleaved in one kv buffer
// (row = 256 bytes: [k_row(128B) | v_row(128B)]) for the attention gather.

constexpr int XS = 136;   // LDS row stride in shorts (pad -> bank rotate)

__global__ __launch_bounds__(256) void gemm_mfma_kernel(
    const ushort_t* __restrict__ Xh, const ushort_t* __restrict__ Xl,
    const ushort_t* __restrict__ Wfh, const ushort_t* __restrict__ Wfl,
    int lw,
    const float* __restrict__ b0, const float* __restrict__ b1,
    const float* __restrict__ b2, const float* __restrict__ b3,
    ushort_t* __restrict__ Oq, char* __restrict__ Okv,
    ushort_t* __restrict__ Os) {
    __shared__ ushort_t XhS[64 * XS];
    __shared__ ushort_t XlS[64 * XS];
    int which = blockIdx.y;
    const ushort_t* wfh = Wfh + (size_t)(lw + which) * 16384;
    const ushort_t* wfl = Wfl + (size_t)(lw + which) * 16384;
    const float* bias = (which == 0) ? b0 : (which == 1) ? b1 : (which == 2) ? b2 : b3;
    bool isfp8 = (which == 1 || which == 2);
    char*     Okv8 = Okv + ((which == 2) ? 128 : 0);     // fp8, row stride 256B
    ushort_t* Obf  = (which == 0) ? Oq : Os;             // bf16, row stride 128

    int w = threadIdx.x >> 6;
    int lane = threadIdx.x & 63;
    int quad = lane >> 4, ln = lane & 15;
    int n0 = w * 32;

    bf16x8 bh[2][4], bl[2][4];
#pragma unroll
    for (int ct = 0; ct < 2; ++ct)
#pragma unroll
        for (int kc = 0; kc < 4; ++kc) {
            int off = (w * 512 + ct * 256 + kc * 64 + lane) * 8;
            bh[ct][kc] = *(const bf16x8*)(wfh + off);
            bl[ct][kc] = *(const bf16x8*)(wfl + off);
        }
    float bias0 = bias[n0 + ln];
    float bias1 = bias[n0 + 16 + ln];

    int rowBase = blockIdx.x * 256;
    int trow = threadIdx.x >> 4;          // staging: 16 rows per instruction
    int tcol = (threadIdx.x & 15) * 8;    // 16B per lane, contiguous per row

    for (int chunk = 0; chunk < 4; ++chunk) {
        int cbase = rowBase + chunk * 64;
        __syncthreads();
#pragma unroll
        for (int rr = 0; rr < 4; ++rr) {
            int lrow = trow + rr * 16;
            int grow = min(cbase + lrow, Nn - 1);
            *(ushort8*)(&XhS[lrow * XS + tcol]) =
                *(const ushort8*)(Xh + (size_t)grow * 128 + tcol);
            *(ushort8*)(&XlS[lrow * XS + tcol]) =
                *(const ushort8*)(Xl + (size_t)grow * 128 + tcol);
        }
        __syncthreads();

#pragma unroll
        for (int rt = 0; rt < 4; ++rt) {
            const ushort_t* ph = &XhS[(rt * 16 + ln) * XS + quad * 8];
            const ushort_t* pl = &XlS[(rt * 16 + ln) * XS + quad * 8];
            bf16x8 ah[4], al[4];
#pragma unroll
            for (int kc = 0; kc < 4; ++kc) {
                ah[kc] = *(const bf16x8*)(ph + kc * 32);
                al[kc] = *(const bf16x8*)(pl + kc * 32);
            }
            f32x4 acc00 = {0.f,0.f,0.f,0.f}, acc01 = {0.f,0.f,0.f,0.f};
            f32x4 acc10 = {0.f,0.f,0.f,0.f}, acc11 = {0.f,0.f,0.f,0.f};
#pragma unroll
            for (int kc = 0; kc < 2; ++kc) {
                int k2 = kc + 2;
                acc00 = __builtin_amdgcn_mfma_f32_16x16x32_bf16(ah[kc], bh[0][kc], acc00, 0, 0, 0);
                acc01 = __builtin_amdgcn_mfma_f32_16x16x32_bf16(ah[kc], bh[1][kc], acc01, 0, 0, 0);
                acc10 = __builtin_amdgcn_mfma_f32_16x16x32_bf16(ah[k2], bh[0][k2], acc10, 0, 0, 0);
                acc11 = __builtin_amdgcn_mfma_f32_16x16x32_bf16(ah[k2], bh[1][k2], acc11, 0, 0, 0);
                acc00 = __builtin_amdgcn_mfma_f32_16x16x32_bf16(ah[kc], bl[0][kc], acc00, 0, 0, 0);
                acc01 = __builtin_amdgcn_mfma_f32_16x16x32_bf16(ah[kc], bl[1][kc], acc01, 0, 0, 0);
                acc10 = __builtin_amdgcn_mfma_f32_16x16x32_bf16(ah[k2], bl[0][k2], acc10, 0, 0, 0);
                acc11 = __builtin_amdgcn_mfma_f32_16x16x32_bf16(ah[k2], bl[1][k2], acc11, 0, 0, 0);
                acc00 = __builtin_amdgcn_mfma_f32_16x16x32_bf16(al[kc], bh[0][kc], acc00, 0, 0, 0);
                acc01 = __builtin_amdgcn_mfma_f32_16x16x32_bf16(al[kc], bh[1][kc], acc01, 0, 0, 0);
                acc10 = __builtin_amdgcn_mfma_f32_16x16x32_bf16(al[k2], bh[0][k2], acc10, 0, 0, 0);
                acc11 = __builtin_amdgcn_mfma_f32_16x16x32_bf16(al[k2], bh[1][k2], acc11, 0, 0, 0);
            }
            int m0 = cbase + rt * 16;
            int orow0 = m0 + quad * 4;
            bool full = (orow0 + 3) < Nn;
#pragma unroll
            for (int reg = 0; reg < 4; ++reg) {
                int orow = orow0 + reg;
                if (full || orow < Nn) {
                    float o0 = acc00[reg] + acc10[reg] + bias0;
                    float o1 = acc01[reg] + acc11[reg] + bias1;
                    if (isfp8) {
                        int pk = __builtin_amdgcn_cvt_pk_fp8_f32(o0, o1, 0, false);
                        size_t ob = (size_t)orow * 256;
                        Okv8[ob + n0 + ln]      = (char)(pk & 0xff);
                        Okv8[ob + n0 + 16 + ln] = (char)((pk >> 8) & 0xff);
                    } else {
                        size_t ob = (size_t)orow * 128;
                        Obf[ob + n0 + ln]      = f2bf(o0);
                        Obf[ob + n0 + 16 + ln] = f2bf(o1);
                    }
                }
            }
        }
    }
}

// ---------------- fused per-node attention (single pass, fp8 kv) ------------
// R11 structure (pk-math R12 variant regressed — reverted). Edge loop
// unrolled 2x: two edges per group in flight (16 gathers/wave concurrent)
// so the ~2 serial loop trips at deg~16 become ~1 dual trip.

__global__ __launch_bounds__(256) void attn_kernel(const ushort_t* __restrict__ q,
                                                   const char* __restrict__ kv,
                                                   const ushort_t* __restrict__ s,
                                                   const int* __restrict__ offsets,
                                                   const int* __restrict__ sorted_src,
                                                   ushort_t* __restrict__ oh,
                                                   ushort_t* __restrict__ ol,
                                                   int write_split) {
    int wid = blockIdx.x * 4 + (threadIdx.x >> 6);
    if (wid >= Nn) return;
    int lane = threadIdx.x & 63;
    int g = lane >> 3;           // edge parity group 0..7
    int gl = lane & 7;           // dim chunk: [gl*16, gl*16+16)
    const ushort_t* qp = q + (size_t)wid * 128 + gl * 16;
    ushort8 qa = *(const ushort8*)(qp);
    ushort8 qb = *(const ushort8*)(qp + 8);
    float qf[16];
#pragma unroll
    for (int j = 0; j < 8; ++j) { qf[j] = bf2f(qa[j]); qf[j + 8] = bf2f(qb[j]); }
    int beg = offsets[wid], end = offsets[wid + 1];

    float l = 0.f;
    float acc[16];
#pragma unroll
    for (int j = 0; j < 16; ++j) acc[j] = 0.f;

    int e = beg + g;
    // dual-edge iterations: both 256B gathers issued before any math
    for (; e + 8 < end; e += 16) {
        int sidx0 = sorted_src[e];
        int sidx1 = sorted_src[e + 8];
        const char* kvp0 = kv + (size_t)sidx0 * 256 + gl * 16;
        const char* kvp1 = kv + (size_t)sidx1 * 256 + gl * 16;
        int4 kw0 = *(const int4*)(kvp0);
        int4 vw0 = *(const int4*)(kvp0 + 128);
        int4 kw1 = *(const int4*)(kvp1);
        int4 vw1 = *(const int4*)(kvp1 + 128);
        float kf0[16], vf0[16], kf1[16], vf1[16];
        fp8x4_to_f32(kw0.x, kf0);      fp8x4_to_f32(kw0.y, kf0 + 4);
        fp8x4_to_f32(kw0.z, kf0 + 8);  fp8x4_to_f32(kw0.w, kf0 + 12);
        fp8x4_to_f32(kw1.x, kf1);      fp8x4_to_f32(kw1.y, kf1 + 4);
        fp8x4_to_f32(kw1.z, kf1 + 8);  fp8x4_to_f32(kw1.w, kf1 + 12);
        float p0 = 0.f, p1 = 0.f;
#pragma unroll
        for (int j = 0; j < 16; ++j) { p0 += qf[j] * kf0[j]; p1 += qf[j] * kf1[j]; }
        p0 += __shfl_xor(p0, 1, 64);
        p1 += __shfl_xor(p1, 1, 64);
        p0 += __shfl_xor(p0, 2, 64);
        p1 += __shfl_xor(p1, 2, 64);
        p0 += __shfl_xor(p0, 4, 64);
        p1 += __shfl_xor(p1, 4, 64);
        float w0 = __expf(p0 * SCALE);
        float w1 = __expf(p1 * SCALE);
        l += w0 + w1;
        fp8x4_to_f32(vw0.x, vf0);      fp8x4_to_f32(vw0.y, vf0 + 4);
        fp8x4_to_f32(vw0.z, vf0 + 8);  fp8x4_to_f32(vw0.w, vf0 + 12);
        fp8x4_to_f32(vw1.x, vf1);      fp8x4_to_f32(vw1.y, vf1 + 4);
        fp8x4_to_f32(vw1.z, vf1 + 8);  fp8x4_to_f32(vw1.w, vf1 + 12);
#pragma unroll
        for (int j = 0; j < 16; ++j) acc[j] += w0 * vf0[j] + w1 * vf1[j];
    }
    if (e < end) {
        int sidx = sorted_src[e];
        const char* kvp = kv + (size_t)sidx * 256 + gl * 16;
        int4 kw = *(const int4*)(kvp);
        int4 vw = *(const int4*)(kvp + 128);
        float kf[16], vf[16];
        fp8x4_to_f32(kw.x, kf);      fp8x4_to_f32(kw.y, kf + 4);
        fp8x4_to_f32(kw.z, kf + 8);  fp8x4_to_f32(kw.w, kf + 12);
        float part = 0.f;
#pragma unroll
        for (int j = 0; j < 16; ++j) part += qf[j] * kf[j];
        part += __shfl_xor(part, 1, 64);
        part += __shfl_xor(part, 2, 64);
        part += __shfl_xor(part, 4, 64);
        float pw = __expf(part * SCALE);
        l += pw;
        fp8x4_to_f32(vw.x, vf);      fp8x4_to_f32(vw.y, vf + 4);
        fp8x4_to_f32(vw.z, vf + 8);  fp8x4_to_f32(vw.w, vf + 12);
#pragma unroll
        for (int j = 0; j < 16; ++j) acc[j] += pw * vf[j];
    }

    // plain-sum merge across the 8 groups (same gl holds same dims)
#pragma unroll
    for (int off = 8; off <= 32; off <<= 1) {
        l += __shfl_xor(l, off, 64);
#pragma unroll
        for (int j = 0; j < 16; ++j) acc[j] += __shfl_xor(acc[j], off, 64);
    }

    if (g == 0) {
        float inv = (l > 0.f) ? (1.0f / l) : 0.f;   // deg==0 -> pure skip
        const ushort_t* sp = s + (size_t)wid * 128 + gl * 16;
        ushort8 sa = *(const ushort8*)(sp);
        ushort8 sb = *(const ushort8*)(sp + 8);
        float ov[16];
#pragma unroll
        for (int j = 0; j < 8; ++j) {
            ov[j]     = fmaxf(acc[j] * inv + bf2f(sa[j]), 0.f);
            ov[j + 8] = fmaxf(acc[j + 8] * inv + bf2f(sb[j]), 0.f);
        }
        if (write_split) {
            ushort8 h0, h1, l0, l1;
#pragma unroll
            for (int j = 0; j < 8; ++j) {
                h0[j] = f2bf(ov[j]);     l0[j] = f2bf(ov[j] - bf2f(h0[j]));
                h1[j] = f2bf(ov[j + 8]); l1[j] = f2bf(ov[j + 8] - bf2f(h1[j]));
            }
            ushort_t* op = oh + (size_t)wid * 128 + gl * 16;
            ushort_t* lp = ol + (size_t)wid * 128 + gl * 16;
            *(ushort8*)(op)     = h0;
            *(ushort8*)(op + 8) = h1;
            *(ushort8*)(lp)     = l0;
            *(ushort8*)(lp + 8) = l1;
        } else {
            ushort8 h0, h1;
#pragma unroll
            for (int j = 0; j < 8; ++j) { h0[j] = f2bf(ov[j]); h1[j] = f2bf(ov[j + 8]); }
            ushort_t* op = oh + (size_t)wid * 128 + gl * 16;
            *(ushort8*)(op)     = h0;
            *(ushort8*)(op + 8) = h1;
        }
    }
}

// ---------------- pooling (bf16 h, coalesced rows, LDS partials) ----------------

__global__ __launch_bounds__(256) void pool_kernel(const ushort_t* __restrict__ hb,
                                                   const int* __restrict__ batch,
                                                   float* __restrict__ pooled) {
    __shared__ float ps[4][128];
    int n0 = blockIdx.x * 256;
    int t = threadIdx.x;
    int lane32 = t & 31, rowgrp = t >> 5;
    for (int i = t; i < 512; i += 256) ((float*)ps)[i] = 0.f;
    __syncthreads();
    int gfirst = batch[min(n0, Nn - 1)];
    int d0 = lane32 * 4;
    float a0 = 0.f, a1 = 0.f, a2 = 0.f, a3 = 0.f;
    int curg = -1;
    for (int rr = 0; rr < 32; ++rr) {
        int n = n0 + rowgrp + rr * 8;
        if (n >= Nn) break;
        int g = batch[n];
        if (g != curg) {
            if (curg >= 0) {
                int slot = curg - gfirst;
                if (slot < 4) {
                    atomicAdd(&ps[slot][d0],     a0);
                    atomicAdd(&ps[slot][d0 + 1], a1);
                    atomicAdd(&ps[slot][d0 + 2], a2);
                    atomicAdd(&ps[slot][d0 + 3], a3);
                } else {
                    atomicAdd(&pooled[curg * Dd + d0],     a0);
                    atomicAdd(&pooled[curg * Dd + d0 + 1], a1);
                    atomicAdd(&pooled[curg * Dd + d0 + 2], a2);
                    atomicAdd(&pooled[curg * Dd + d0 + 3], a3);
                }
                a0 = a1 = a2 = a3 = 0.f;
            }
            curg = g;
        }
        ushort4 hv = *(const ushort4*)(hb + (size_t)n * 128 + d0);
        a0 += bf2f(hv.x); a1 += bf2f(hv.y); a2 += bf2f(hv.z); a3 += bf2f(hv.w);
    }
    if (curg >= 0) {
        int slot = curg - gfirst;
        if (slot < 4) {
            atomicAdd(&ps[slot][d0],     a0);
            atomicAdd(&ps[slot][d0 + 1], a1);
            atomicAdd(&ps[slot][d0 + 2], a2);
            atomicAdd(&ps[slot][d0 + 3], a3);
        } else {
            atomicAdd(&pooled[curg * Dd + d0],     a0);
            atomicAdd(&pooled[curg * Dd + d0 + 1], a1);
            atomicAdd(&pooled[curg * Dd + d0 + 2], a2);
            atomicAdd(&pooled[curg * Dd + d0 + 3], a3);
        }
    }
    __syncthreads();
    int glast = batch[min(n0 + 255, Nn - 1)];
    int nslots = min(glast - gfirst + 1, 4);
    for (int i = t; i < nslots * 128; i += 256) {
        int slot = i >> 7, d = i & 127;
        atomicAdd(&pooled[(gfirst + slot) * Dd + d], ps[slot][d]);
    }
}

__global__ __launch_bounds__(64) void mlp_kernel(const float* __restrict__ pooled,
                                                 const int* __restrict__ startg,
                                                 const int* __restrict__ endg,
                                                 const float* __restrict__ Wc1,
                                                 const float* __restrict__ bc1,
                                                 const float* __restrict__ Wc2,
                                                 const float* __restrict__ bc2,
                                                 float* __restrict__ out) {
    __shared__ float pm[128];
    __shared__ float hid[64];
    int g = blockIdx.x, t = threadIdx.x;   // 64 threads
    float cnt = fmaxf((float)(endg[g] - startg[g]), 1.0f);
    float invc = 1.0f / cnt;
    pm[t]      = pooled[g * 128 + t] * invc;
    pm[t + 64] = pooled[g * 128 + 64 + t] * invc;
    __syncthreads();
    float acc = bc1[t];
    for (int i = 0; i < 128; ++i) acc += pm[i] * Wc1[t * 128 + i];
    hid[t] = fmaxf(acc, 0.f);
    __syncthreads();
    if (t < 2) {
        float a = bc2[t];
        for (int i = 0; i < 64; ++i) a += hid[i] * Wc2[t * 64 + i];
        out[g * 2 + t] = a;
    }
}

// ---------------- launch ----------------

extern "C" void kernel_launch(void* const* d_in, const int* in_sizes, int n_in,
                              void* d_out, int out_size, void* d_ws, size_t ws_size,
                              hipStream_t stream) {
    const float* x   = (const float*)d_in[0];
    const int*   ei  = (const int*)d_in[1];
    const int* batch = (const int*)d_in[2];
    const float* W[2][4];
    const float* B[2][4];
    for (int l = 0; l < 2; ++l) {
        for (int j = 0; j < 4; ++j) W[l][j] = (const float*)d_in[3 + l * 8 + j];
        for (int j = 0; j < 4; ++j) B[l][j] = (const float*)d_in[3 + l * 8 + 4 + j];
    }
    const float* Wc1 = (const float*)d_in[19];
    const float* bc1 = (const float*)d_in[20];
    const float* Wc2 = (const float*)d_in[21];
    const float* bc2 = (const float*)d_in[22];
    float* out = (float*)d_out;

    const int* src = ei;        // edge_index[0]
    const int* dst = ei + Ee;   // edge_index[1]

    char* p = (char*)d_ws;
    auto alloc = [&](size_t bytes) {
        void* r = (void*)p;
        p += (bytes + 255) & ~(size_t)255;
        return r;
    };
    ushort_t* q  = (ushort_t*)alloc((size_t)Nn * 128 * 2);  // bf16
    char*     kv = (char*)alloc((size_t)Nn * 256);          // fp8 [k_row|v_row]
    ushort_t* ss = (ushort_t*)alloc((size_t)Nn * 128 * 2);  // bf16
    ushort_t* hb = (ushort_t*)alloc((size_t)Nn * 128 * 2);  // bf16 layer-2 h
    ushort_t* Xh = (ushort_t*)alloc((size_t)Nn * 128 * 2);
    ushort_t* Xl = (ushort_t*)alloc((size_t)Nn * 128 * 2);
    ushort_t* Wfh = (ushort_t*)alloc((size_t)8 * 16384 * 2);
    ushort_t* Wfl = (ushort_t*)alloc((size_t)8 * 16384 * 2);
    char* zbase = p;  // region zeroed each launch
    int*   counts = (int*)alloc(Nn * 4);
    int*   startg = (int*)alloc(Gg * 4);
    int*   endg   = (int*)alloc(Gg * 4);
    float* pooled = (float*)alloc(Gg * Dd * 4);
    size_t zbytes = (size_t)(p - zbase);
    int* offsets    = (int*)alloc((size_t)(Nn + 1) * 4);
    int* cursor     = (int*)alloc(Nn * 4);
    int* blockSums  = (int*)alloc(256 * 4);
    int* sorted_src = (int*)alloc((size_t)Ee * 4);

    hipMemsetAsync(zbase, 0, zbytes, stream);

    constexpr int NB = (Nn + 255) / 256;  // 196 scan blocks
    hist_bound_kernel<<<EB + NBD, 256, 0, stream>>>(dst, counts, batch, startg, endg);
    scan1_kernel<<<NB, 256, 0, stream>>>(counts, offsets, blockSums);
    scan2_kernel<<<1, 256, 0, stream>>>(blockSums, NB);
    scan3_kernel<<<NB, 256, 0, stream>>>(offsets, blockSums, cursor);
    scatter_kernel<<<(Ee + 255) / 256, 256, 0, stream>>>(src, dst, cursor, sorted_src);

    convw_kernel<<<64, 256, 0, stream>>>(W[0][0], W[0][1], W[0][2], W[0][3],
                                         W[1][0], W[1][1], W[1][2], W[1][3], Wfh, Wfl);

    constexpr int N4 = Nn * Dd / 4;
    dim3 ggrid((Nn + 255) / 256, 4);      // 196 row-groups x 4 output matrices

    // layer 0
    convx_kernel<<<(N4 + 255) / 256, 256, 0, stream>>>(x, Xh, Xl, N4);
    gemm_mfma_kernel<<<ggrid, 256, 0, stream>>>(Xh, Xl, Wfh, Wfl, 0,
                                                B[0][0], B[0][1], B[0][2], B[0][3],
                                                q, kv, ss);
    // layer-1 attn writes split-bf16 h straight into Xh/Xl
    attn_kernel<<<(Nn + 3) / 4, 256, 0, stream>>>(q, kv, ss, offsets, sorted_src,
                                                  Xh, Xl, 1);
    // layer 1
    gemm_mfma_kernel<<<ggrid, 256, 0, stream>>>(Xh, Xl, Wfh, Wfl, 4,
                                                B[1][0], B[1][1], B[1][2], B[1][3],
                                                q, kv, ss);
    attn_kernel<<<(Nn + 3) / 4, 256, 0, stream>>>(q, kv, ss, offsets, sorted_src,
                                                  hb, hb, 0);

    pool_kernel<<<(Nn + 255) / 256, 256, 0, stream>>>(hb, batch, pooled);
    mlp_kernel<<<Gg, 64, 0, stream>>>(pooled, startg, endg, Wc1, bc1, Wc2, bc2, out);
}

// Round 15
// 377.288 us; speedup vs baseline: 1.0779x; 1.0779x over previous
//
#include <hip/hip_runtime.h>
#include <math.h>

typedef __bf16 bf16x8 __attribute__((ext_vector_type(8)));
typedef float  f32x4  __attribute__((ext_vector_type(4)));
typedef float  f32x2  __attribute__((ext_vector_type(2)));
typedef unsigned short ushort_t;
typedef unsigned short ushort8 __attribute__((ext_vector_type(8)));

// Problem constants (fixed by the reference).
constexpr int Nn = 50000;   // nodes
constexpr int Ee = 800000;  // edges
constexpr int Dd = 128;     // feature dim
constexpr int Gg = 64;      // graphs
constexpr float SCALE = 0.08838834764831845f; // 1/sqrt(128)

__device__ inline ushort_t f2bf(float f) {
    unsigned u = __float_as_uint(f);
    unsigned r = (u + 0x7FFF + ((u >> 16) & 1)) >> 16;   // RNE truncate to bf16
    return (ushort_t)r;
}
__device__ inline float bf2f(ushort_t b) { return __uint_as_float(((unsigned)b) << 16); }

// 4 packed fp8 (e4m3) -> 4 floats via HW packed converts
__device__ inline void fp8x4_to_f32(int w, float* out) {
    f32x2 lo = __builtin_amdgcn_cvt_pk_f32_fp8(w, false);
    f32x2 hi = __builtin_amdgcn_cvt_pk_f32_fp8(w, true);
    out[0] = lo[0]; out[1] = lo[1]; out[2] = hi[0]; out[3] = hi[1];
}

// ---------------- fused prep: hist + graph bounds + convw + convx ------------
// All four are mutually independent (hist: dst->counts; bound: batch->startg/
// endg; convw: W->Wf; convx: x->Xh/Xl) -> one launch, blocks co-schedule.

constexpr int EB  = (Ee + 255) / 256;   // 3125 hist blocks
constexpr int NBD = (Nn + 255) / 256;   // 196 bound blocks
constexpr int CWB = 64;                 // convw blocks
constexpr int N4  = Nn * Dd / 4;        // 1.6M float4s
constexpr int CXB = N4 / 256;           // 6250 convx blocks

__global__ __launch_bounds__(256) void prep_kernel(
    const int* __restrict__ dst, int* __restrict__ counts,
    const int* __restrict__ batch, int* __restrict__ startg, int* __restrict__ endg,
    const float* w0, const float* w1, const float* w2, const float* w3,
    const float* w4, const float* w5, const float* w6, const float* w7,
    ushort_t* __restrict__ Wfh, ushort_t* __restrict__ Wfl,
    const float* __restrict__ x, ushort_t* __restrict__ Xh, ushort_t* __restrict__ Xl) {
    int b = blockIdx.x;
    if (b < EB) {                                   // ---- histogram
        int e = b * 256 + threadIdx.x;
        if (e < Ee) atomicAdd(&counts[dst[e]], 1);
    } else if (b < EB + NBD) {                      // ---- graph bounds
        int n = (b - EB) * 256 + threadIdx.x;
        if (n >= Nn) return;
        int g = batch[n];
        if (n == Nn - 1 || batch[n + 1] != g) endg[g] = n + 1;
        if (n == 0 || batch[n - 1] != g) startg[g] = n;
    } else if (b < EB + NBD + CWB) {                // ---- fragment-order weights
        const float* ws[8] = {w0, w1, w2, w3, w4, w5, w6, w7};
        int b2 = b - (EB + NBD);
        int m = b2 >> 3;
        int tt = (b2 & 7) * 256 + threadIdx.x;      // 0..2047 fragment slots
        int lane = tt & 63;
        int ln = lane & 15, quad = lane >> 4;
        int n = (tt >> 9) * 32 + ((tt >> 8) & 1) * 16 + ln;
        int k0 = ((tt >> 6) & 3) * 32 + quad * 8;
        const float* srcp = ws[m] + n * 128 + k0;
        float4 a = *(const float4*)(srcp);
        float4 bb = *(const float4*)(srcp + 4);
        float e[8] = {a.x, a.y, a.z, a.w, bb.x, bb.y, bb.z, bb.w};
        ushort8 h, l;
#pragma unroll
        for (int j = 0; j < 8; ++j) {
            h[j] = f2bf(e[j]);
            l[j] = f2bf(e[j] - bf2f(h[j]));
        }
        size_t o = (size_t)m * 16384 + (size_t)tt * 8;
        *(ushort8*)(Wfh + o) = h;
        *(ushort8*)(Wfl + o) = l;
    } else {                                        // ---- split-bf16 convx
        int i = (b - (EB + NBD + CWB)) * 256 + threadIdx.x;
        if (i >= N4) return;
        float4 xv = ((const float4*)x)[i];
        ushort4 h, l;
        h.x = f2bf(xv.x); l.x = f2bf(xv.x - bf2f(h.x));
        h.y = f2bf(xv.y); l.y = f2bf(xv.y - bf2f(h.y));
        h.z = f2bf(xv.z); l.z = f2bf(xv.z - bf2f(h.z));
        h.w = f2bf(xv.w); l.w = f2bf(xv.w - bf2f(h.w));
        ((ushort4*)Xh)[i] = h;
        ((ushort4*)Xl)[i] = l;
    }
}

// ---------------- scans (CSR offsets) ----------------

__global__ __launch_bounds__(256) void scan1_kernel(const int* __restrict__ counts,
                                                    int* __restrict__ offsets,
                                                    int* __restrict__ blockSums) {
    __shared__ int sh[256];
    int i = blockIdx.x * 256 + threadIdx.x;
    int v = (i < Nn) ? counts[i] : 0;
    sh[threadIdx.x] = v;
    __syncthreads();
    for (int off = 1; off < 256; off <<= 1) {
        int t = (threadIdx.x >= off) ? sh[threadIdx.x - off] : 0;
        __syncthreads();
        sh[threadIdx.x] += t;
        __syncthreads();
    }
    if (i < Nn) offsets[i] = sh[threadIdx.x] - v;   // exclusive within block
    if (threadIdx.x == 255) blockSums[blockIdx.x] = sh[255];
}

__global__ __launch_bounds__(256) void scan2_kernel(int* __restrict__ blockSums, int nb) {
    __shared__ int sh[256];
    int t = threadIdx.x;
    int v = (t < nb) ? blockSums[t] : 0;
    sh[t] = v;
    __syncthreads();
    for (int off = 1; off < 256; off <<= 1) {
        int u = (t >= off) ? sh[t - off] : 0;
        __syncthreads();
        sh[t] += u;
        __syncthreads();
    }
    if (t < nb) blockSums[t] = sh[t] - v;           // exclusive across blocks
}

__global__ __launch_bounds__(256) void scan3_kernel(int* __restrict__ offsets,
                                                    const int* __restrict__ blockSums,
                                                    int* __restrict__ cursor) {
    int i = blockIdx.x * 256 + threadIdx.x;
    if (i < Nn) {
        int o = offsets[i] + blockSums[blockIdx.x];
        offsets[i] = o;
        cursor[i] = o;
    }
    if (i == 0) offsets[Nn] = Ee;
}

// ---------------- MFMA split-bf16 GEMM body: Y = X @ W^T + b ----------------
// LDS-staged X (coalesced 4KB loads), fragment-order weights.
// q,s out bf16; k,v out FP8-e4m3 interleaved in kv (row = 256B [k|v]).

constexpr int XS = 136;   // LDS row stride in shorts (pad -> bank rotate)

__device__ void gemm_body(int bx, int which,
    const ushort_t* __restrict__ Xh, const ushort_t* __restrict__ Xl,
    const ushort_t* __restrict__ Wfh, const ushort_t* __restrict__ Wfl,
    int lw,
    const float* __restrict__ b0, const float* __restrict__ b1,
    const float* __restrict__ b2, const float* __restrict__ b3,
    ushort_t* __restrict__ Oq, char* __restrict__ Okv,
    ushort_t* __restrict__ Os) {
    __shared__ ushort_t XhS[64 * XS];
    __shared__ ushort_t XlS[64 * XS];
    const ushort_t* wfh = Wfh + (size_t)(lw + which) * 16384;
    const ushort_t* wfl = Wfl + (size_t)(lw + which) * 16384;
    const float* bias = (which == 0) ? b0 : (which == 1) ? b1 : (which == 2) ? b2 : b3;
    bool isfp8 = (which == 1 || which == 2);
    char*     Okv8 = Okv + ((which == 2) ? 128 : 0);     // fp8, row stride 256B
    ushort_t* Obf  = (which == 0) ? Oq : Os;             // bf16, row stride 128

    int w = threadIdx.x >> 6;
    int lane = threadIdx.x & 63;
    int quad = lane >> 4, ln = lane & 15;
    int n0 = w * 32;

    bf16x8 bh[2][4], bl[2][4];
#pragma unroll
    for (int ct = 0; ct < 2; ++ct)
#pragma unroll
        for (int kc = 0; kc < 4; ++kc) {
            int off = (w * 512 + ct * 256 + kc * 64 + lane) * 8;
            bh[ct][kc] = *(const bf16x8*)(wfh + off);
            bl[ct][kc] = *(const bf16x8*)(wfl + off);
        }
    float bias0 = bias[n0 + ln];
    float bias1 = bias[n0 + 16 + ln];

    int rowBase = bx * 256;
    int trow = threadIdx.x >> 4;          // staging: 16 rows per instruction
    int tcol = (threadIdx.x & 15) * 8;    // 16B per lane, contiguous per row

    for (int chunk = 0; chunk < 4; ++chunk) {
        int cbase = rowBase + chunk * 64;
        __syncthreads();
#pragma unroll
        for (int rr = 0; rr < 4; ++rr) {
            int lrow = trow + rr * 16;
            int grow = min(cbase + lrow, Nn - 1);
            *(ushort8*)(&XhS[lrow * XS + tcol]) =
                *(const ushort8*)(Xh + (size_t)grow * 128 + tcol);
            *(ushort8*)(&XlS[lrow * XS + tcol]) =
                *(const ushort8*)(Xl + (size_t)grow * 128 + tcol);
        }
        __syncthreads();

#pragma unroll
        for (int rt = 0; rt < 4; ++rt) {
            const ushort_t* ph = &XhS[(rt * 16 + ln) * XS + quad * 8];
            const ushort_t* pl = &XlS[(rt * 16 + ln) * XS + quad * 8];
            bf16x8 ah[4], al[4];
#pragma unroll
            for (int kc = 0; kc < 4; ++kc) {
                ah[kc] = *(const bf16x8*)(ph + kc * 32);
                al[kc] = *(const bf16x8*)(pl + kc * 32);
            }
            f32x4 acc00 = {0.f,0.f,0.f,0.f}, acc01 = {0.f,0.f,0.f,0.f};
            f32x4 acc10 = {0.f,0.f,0.f,0.f}, acc11 = {0.f,0.f,0.f,0.f};
#pragma unroll
            for (int kc = 0; kc < 2; ++kc) {
                int k2 = kc + 2;
                acc00 = __builtin_amdgcn_mfma_f32_16x16x32_bf16(ah[kc], bh[0][kc], acc00, 0, 0, 0);
                acc01 = __builtin_amdgcn_mfma_f32_16x16x32_bf16(ah[kc], bh[1][kc], acc01, 0, 0, 0);
                acc10 = __builtin_amdgcn_mfma_f32_16x16x32_bf16(ah[k2], bh[0][k2], acc10, 0, 0, 0);
                acc11 = __builtin_amdgcn_mfma_f32_16x16x32_bf16(ah[k2], bh[1][k2], acc11, 0, 0, 0);
                acc00 = __builtin_amdgcn_mfma_f32_16x16x32_bf16(ah[kc], bl[0][kc], acc00, 0, 0, 0);
                acc01 = __builtin_amdgcn_mfma_f32_16x16x32_bf16(ah[kc], bl[1][kc], acc01, 0, 0, 0);
                acc10 = __builtin_amdgcn_mfma_f32_16x16x32_bf16(ah[k2], bl[0][k2], acc10, 0, 0, 0);
                acc11 = __builtin_amdgcn_mfma_f32_16x16x32_bf16(ah[k2], bl[1][k2], acc11, 0, 0, 0);
                acc00 = __builtin_amdgcn_mfma_f32_16x16x32_bf16(al[kc], bh[0][kc], acc00, 0, 0, 0);
                acc01 = __builtin_amdgcn_mfma_f32_16x16x32_bf16(al[kc], bh[1][kc], acc01, 0, 0, 0);
                acc10 = __builtin_amdgcn_mfma_f32_16x16x32_bf16(al[k2], bh[0][k2], acc10, 0, 0, 0);
                acc11 = __builtin_amdgcn_mfma_f32_16x16x32_bf16(al[k2], bh[1][k2], acc11, 0, 0, 0);
            }
            int m0 = cbase + rt * 16;
            int orow0 = m0 + quad * 4;
            bool full = (orow0 + 3) < Nn;
#pragma unroll
            for (int reg = 0; reg < 4; ++reg) {
                int orow = orow0 + reg;
                if (full || orow < Nn) {
                    float o0 = acc00[reg] + acc10[reg] + bias0;
                    float o1 = acc01[reg] + acc11[reg] + bias1;
                    if (isfp8) {
                        int pk = __builtin_amdgcn_cvt_pk_fp8_f32(o0, o1, 0, false);
                        size_t ob = (size_t)orow * 256;
                        Okv8[ob + n0 + ln]      = (char)(pk & 0xff);
                        Okv8[ob + n0 + 16 + ln] = (char)((pk >> 8) & 0xff);
                    } else {
                        size_t ob = (size_t)orow * 128;
                        Obf[ob + n0 + ln]      = f2bf(o0);
                        Obf[ob + n0 + 16 + ln] = f2bf(o1);
                    }
                }
            }
        }
    }
}

// layer-1 gemm (2D grid, plain)
__global__ __launch_bounds__(256) void gemm_mfma_kernel(
    const ushort_t* __restrict__ Xh, const ushort_t* __restrict__ Xl,
    const ushort_t* __restrict__ Wfh, const ushort_t* __restrict__ Wfl,
    int lw,
    const float* __restrict__ b0, const float* __restrict__ b1,
    const float* __restrict__ b2, const float* __restrict__ b3,
    ushort_t* __restrict__ Oq, char* __restrict__ Okv,
    ushort_t* __restrict__ Os) {
    gemm_body(blockIdx.x, blockIdx.y, Xh, Xl, Wfh, Wfl, lw, b0, b1, b2, b3, Oq, Okv, Os);
}

// layer-0 gemm fused with edge scatter (independent work, one launch ->
// scatter hides under the gemm). 1-D grid: 784 gemm blocks + 3125 scatter.
constexpr int G0B = 196 * 4;

__global__ __launch_bounds__(256) void gemm0_scatter_kernel(
    const ushort_t* __restrict__ Xh, const ushort_t* __restrict__ Xl,
    const ushort_t* __restrict__ Wfh, const ushort_t* __restrict__ Wfl,
    const float* __restrict__ b0, const float* __restrict__ b1,
    const float* __restrict__ b2, const float* __restrict__ b3,
    ushort_t* __restrict__ Oq, char* __restrict__ Okv, ushort_t* __restrict__ Os,
    const int* __restrict__ src, const int* __restrict__ dst,
    int* __restrict__ cursor, int* __restrict__ sorted_src) {
    int b = blockIdx.x;
    if (b < G0B) {
        gemm_body(b % 196, b / 196, Xh, Xl, Wfh, Wfl, 0, b0, b1, b2, b3, Oq, Okv, Os);
    } else {
        int e = (b - G0B) * 256 + threadIdx.x;
        if (e < Ee) {
            int d = dst[e];
            int pos = atomicAdd(&cursor[d], 1);
            sorted_src[pos] = src[e];
        }
    }
}

// ---------------- fused per-node attention (single pass, fp8 kv) ------------
// R11 body verbatim — the verified best (R12 pk-math, R13 unroll, R14 index
// burst all regressed or broke; VGPR pressure / shfl divergence).
// alpha bounded -> no max subtraction. 8 groups x 8 lanes; lane owns dims
// [gl*16,+16); each edge reads ONE contiguous 256B fp8 kv block.

__global__ __launch_bounds__(256) void attn_kernel(const ushort_t* __restrict__ q,
                                                   const char* __restrict__ kv,
                                                   const ushort_t* __restrict__ s,
                                                   const int* __restrict__ offsets,
                                                   const int* __restrict__ sorted_src,
                                                   ushort_t* __restrict__ oh,
                                                   ushort_t* __restrict__ ol,
                                                   int write_split) {
    int wid = blockIdx.x * 4 + (threadIdx.x >> 6);
    if (wid >= Nn) return;
    int lane = threadIdx.x & 63;
    int g = lane >> 3;           // edge parity group 0..7
    int gl = lane & 7;           // dim chunk: [gl*16, gl*16+16)
    const ushort_t* qp = q + (size_t)wid * 128 + gl * 16;
    ushort8 qa = *(const ushort8*)(qp);
    ushort8 qb = *(const ushort8*)(qp + 8);
    float qf[16];
#pragma unroll
    for (int j = 0; j < 8; ++j) { qf[j] = bf2f(qa[j]); qf[j + 8] = bf2f(qb[j]); }
    int beg = offsets[wid], end = offsets[wid + 1];

    float l = 0.f;
    float acc[16];
#pragma unroll
    for (int j = 0; j < 16; ++j) acc[j] = 0.f;

    for (int e = beg + g; e < end; e += 8) {
        int sidx = sorted_src[e];
        const char* kvp = kv + (size_t)sidx * 256 + gl * 16;
        int4 kw = *(const int4*)(kvp);
        int4 vw = *(const int4*)(kvp + 128);
        float kf[16], vf[16];
        fp8x4_to_f32(kw.x, kf);      fp8x4_to_f32(kw.y, kf + 4);
        fp8x4_to_f32(kw.z, kf + 8);  fp8x4_to_f32(kw.w, kf + 12);
        float part = 0.f;
#pragma unroll
        for (int j = 0; j < 16; ++j) part += qf[j] * kf[j];
        part += __shfl_xor(part, 1, 64);
        part += __shfl_xor(part, 2, 64);
        part += __shfl_xor(part, 4, 64);
        float pw = __expf(part * SCALE);
        l += pw;
        fp8x4_to_f32(vw.x, vf);      fp8x4_to_f32(vw.y, vf + 4);
        fp8x4_to_f32(vw.z, vf + 8);  fp8x4_to_f32(vw.w, vf + 12);
#pragma unroll
        for (int j = 0; j < 16; ++j) acc[j] += pw * vf[j];
    }

    // plain-sum merge across the 8 groups (same gl holds same dims)
#pragma unroll
    for (int off = 8; off <= 32; off <<= 1) {
        l += __shfl_xor(l, off, 64);
#pragma unroll
        for (int j = 0; j < 16; ++j) acc[j] += __shfl_xor(acc[j], off, 64);
    }

    if (g == 0) {
        float inv = (l > 0.f) ? (1.0f / l) : 0.f;   // deg==0 -> pure skip
        const ushort_t* sp = s + (size_t)wid * 128 + gl * 16;
        ushort8 sa = *(const ushort8*)(sp);
        ushort8 sb = *(const ushort8*)(sp + 8);
        float ov[16];
#pragma unroll
        for (int j = 0; j < 8; ++j) {
            ov[j]     = fmaxf(acc[j] * inv + bf2f(sa[j]), 0.f);
            ov[j + 8] = fmaxf(acc[j + 8] * inv + bf2f(sb[j]), 0.f);
        }
        if (write_split) {
            ushort8 h0, h1, l0, l1;
#pragma unroll
            for (int j = 0; j < 8; ++j) {
                h0[j] = f2bf(ov[j]);     l0[j] = f2bf(ov[j] - bf2f(h0[j]));
                h1[j] = f2bf(ov[j + 8]); l1[j] = f2bf(ov[j + 8] - bf2f(h1[j]));
            }
            ushort_t* op = oh + (size_t)wid * 128 + gl * 16;
            ushort_t* lp = ol + (size_t)wid * 128 + gl * 16;
            *(ushort8*)(op)     = h0;
            *(ushort8*)(op + 8) = h1;
            *(ushort8*)(lp)     = l0;
            *(ushort8*)(lp + 8) = l1;
        } else {
            ushort8 h0, h1;
#pragma unroll
            for (int j = 0; j < 8; ++j) { h0[j] = f2bf(ov[j]); h1[j] = f2bf(ov[j + 8]); }
            ushort_t* op = oh + (size_t)wid * 128 + gl * 16;
            *(ushort8*)(op)     = h0;
            *(ushort8*)(op + 8) = h1;
        }
    }
}

// ---------------- pooling (bf16 h, coalesced rows, LDS partials) ----------------

__global__ __launch_bounds__(256) void pool_kernel(const ushort_t* __restrict__ hb,
                                                   const int* __restrict__ batch,
                                                   float* __restrict__ pooled) {
    __shared__ float ps[4][128];
    int n0 = blockIdx.x * 256;
    int t = threadIdx.x;
    int lane32 = t & 31, rowgrp = t >> 5;
    for (int i = t; i < 512; i += 256) ((float*)ps)[i] = 0.f;
    __syncthreads();
    int gfirst = batch[min(n0, Nn - 1)];
    int d0 = lane32 * 4;
    float a0 = 0.f, a1 = 0.f, a2 = 0.f, a3 = 0.f;
    int curg = -1;
    for (int rr = 0; rr < 32; ++rr) {
        int n = n0 + rowgrp + rr * 8;
        if (n >= Nn) break;
        int g = batch[n];
        if (g != curg) {
            if (curg >= 0) {
                int slot = curg - gfirst;
                if (slot < 4) {
                    atomicAdd(&ps[slot][d0],     a0);
                    atomicAdd(&ps[slot][d0 + 1], a1);
                    atomicAdd(&ps[slot][d0 + 2], a2);
                    atomicAdd(&ps[slot][d0 + 3], a3);
                } else {
                    atomicAdd(&pooled[curg * Dd + d0],     a0);
                    atomicAdd(&pooled[curg * Dd + d0 + 1], a1);
                    atomicAdd(&pooled[curg * Dd + d0 + 2], a2);
                    atomicAdd(&pooled[curg * Dd + d0 + 3], a3);
                }
                a0 = a1 = a2 = a3 = 0.f;
            }
            curg = g;
        }
        ushort4 hv = *(const ushort4*)(hb + (size_t)n * 128 + d0);
        a0 += bf2f(hv.x); a1 += bf2f(hv.y); a2 += bf2f(hv.z); a3 += bf2f(hv.w);
    }
    if (curg >= 0) {
        int slot = curg - gfirst;
        if (slot < 4) {
            atomicAdd(&ps[slot][d0],     a0);
            atomicAdd(&ps[slot][d0 + 1], a1);
            atomicAdd(&ps[slot][d0 + 2], a2);
            atomicAdd(&ps[slot][d0 + 3], a3);
        } else {
            atomicAdd(&pooled[curg * Dd + d0],     a0);
            atomicAdd(&pooled[curg * Dd + d0 + 1], a1);
            atomicAdd(&pooled[curg * Dd + d0 + 2], a2);
            atomicAdd(&pooled[curg * Dd + d0 + 3], a3);
        }
    }
    __syncthreads();
    int glast = batch[min(n0 + 255, Nn - 1)];
    int nslots = min(glast - gfirst + 1, 4);
    for (int i = t; i < nslots * 128; i += 256) {
        int slot = i >> 7, d = i & 127;
        atomicAdd(&pooled[(gfirst + slot) * Dd + d], ps[slot][d]);
    }
}

__global__ __launch_bounds__(64) void mlp_kernel(const float* __restrict__ pooled,
                                                 const int* __restrict__ startg,
                                                 const int* __restrict__ endg,
                                                 const float* __restrict__ Wc1,
                                                 const float* __restrict__ bc1,
                                                 const float* __restrict__ Wc2,
                                                 const float* __restrict__ bc2,
                                                 float* __restrict__ out) {
    __shared__ float pm[128];
    __shared__ float hid[64];
    int g = blockIdx.x, t = threadIdx.x;   // 64 threads
    float cnt = fmaxf((float)(endg[g] - startg[g]), 1.0f);
    float invc = 1.0f / cnt;
    pm[t]      = pooled[g * 128 + t] * invc;
    pm[t + 64] = pooled[g * 128 + 64 + t] * invc;
    __syncthreads();
    float acc = bc1[t];
    for (int i = 0; i < 128; ++i) acc += pm[i] * Wc1[t * 128 + i];
    hid[t] = fmaxf(acc, 0.f);
    __syncthreads();
    if (t < 2) {
        float a = bc2[t];
        for (int i = 0; i < 64; ++i) a += hid[i] * Wc2[t * 64 + i];
        out[g * 2 + t] = a;
    }
}

// ---------------- launch ----------------

extern "C" void kernel_launch(void* const* d_in, const int* in_sizes, int n_in,
                              void* d_out, int out_size, void* d_ws, size_t ws_size,
                              hipStream_t stream) {
    const float* x   = (const float*)d_in[0];
    const int*   ei  = (const int*)d_in[1];
    const int* batch = (const int*)d_in[2];
    const float* W[2][4];
    const float* B[2][4];
    for (int l = 0; l < 2; ++l) {
        for (int j = 0; j < 4; ++j) W[l][j] = (const float*)d_in[3 + l * 8 + j];
        for (int j = 0; j < 4; ++j) B[l][j] = (const float*)d_in[3 + l * 8 + 4 + j];
    }
    const float* Wc1 = (const float*)d_in[19];
    const float* bc1 = (const float*)d_in[20];
    const float* Wc2 = (const float*)d_in[21];
    const float* bc2 = (const float*)d_in[22];
    float* out = (float*)d_out;

    const int* src = ei;        // edge_index[0]
    const int* dst = ei + Ee;   // edge_index[1]

    char* p = (char*)d_ws;
    auto alloc = [&](size_t bytes) {
        void* r = (void*)p;
        p += (bytes + 255) & ~(size_t)255;
        return r;
    };
    ushort_t* q  = (ushort_t*)alloc((size_t)Nn * 128 * 2);  // bf16
    char*     kv = (char*)alloc((size_t)Nn * 256);          // fp8 [k_row|v_row]
    ushort_t* ss = (ushort_t*)alloc((size_t)Nn * 128 * 2);  // bf16
    ushort_t* hb = (ushort_t*)alloc((size_t)Nn * 128 * 2);  // bf16 layer-2 h
    ushort_t* Xh = (ushort_t*)alloc((size_t)Nn * 128 * 2);
    ushort_t* Xl = (ushort_t*)alloc((size_t)Nn * 128 * 2);
    ushort_t* Wfh = (ushort_t*)alloc((size_t)8 * 16384 * 2);
    ushort_t* Wfl = (ushort_t*)alloc((size_t)8 * 16384 * 2);
    char* zbase = p;  // region zeroed each launch
    int*   counts = (int*)alloc(Nn * 4);
    int*   startg = (int*)alloc(Gg * 4);
    int*   endg   = (int*)alloc(Gg * 4);
    float* pooled = (float*)alloc(Gg * Dd * 4);
    size_t zbytes = (size_t)(p - zbase);
    int* offsets    = (int*)alloc((size_t)(Nn + 1) * 4);
    int* cursor     = (int*)alloc(Nn * 4);
    int* blockSums  = (int*)alloc(256 * 4);
    int* sorted_src = (int*)alloc((size_t)Ee * 4);

    hipMemsetAsync(zbase, 0, zbytes, stream);

    constexpr int NB = (Nn + 255) / 256;  // 196 scan blocks

    // prep: hist + bounds + convw + convx (independent, one launch)
    prep_kernel<<<EB + NBD + CWB + CXB, 256, 0, stream>>>(
        dst, counts, batch, startg, endg,
        W[0][0], W[0][1], W[0][2], W[0][3], W[1][0], W[1][1], W[1][2], W[1][3],
        Wfh, Wfl, x, Xh, Xl);
    scan1_kernel<<<NB, 256, 0, stream>>>(counts, offsets, blockSums);
    scan2_kernel<<<1, 256, 0, stream>>>(blockSums, NB);
    scan3_kernel<<<NB, 256, 0, stream>>>(offsets, blockSums, cursor);

    // layer-0 gemm fused with scatter (independent; scatter hides under gemm)
    gemm0_scatter_kernel<<<G0B + EB, 256, 0, stream>>>(
        Xh, Xl, Wfh, Wfl, B[0][0], B[0][1], B[0][2], B[0][3],
        q, kv, ss, src, dst, cursor, sorted_src);

    // layer-0 attn writes split-bf16 h straight into Xh/Xl
    attn_kernel<<<(Nn + 3) / 4, 256, 0, stream>>>(q, kv, ss, offsets, sorted_src,
                                                  Xh, Xl, 1);
    // layer 1
    dim3 ggrid(196, 4);
    gemm_mfma_kernel<<<ggrid, 256, 0, stream>>>(Xh, Xl, Wfh, Wfl, 4,
                                                B[1][0], B[1][1], B[1][2], B[1][3],
                                                q, kv, ss);
    attn_kernel<<<(Nn + 3) / 4, 256, 0, stream>>>(q, kv, ss, offsets, sorted_src,
                                                  hb, hb, 0);

    pool_kernel<<<(Nn + 255) / 256, 256, 0, stream>>>(hb, batch, pooled);
    mlp_kernel<<<Gg, 64, 0, stream>>>(pooled, startg, endg, Wc1, bc1, Wc2, bc2, out);
}

// Round 16
// 341.016 us; speedup vs baseline: 1.1925x; 1.1064x over previous
//
#include <hip/hip_runtime.h>
#include <math.h>

typedef __bf16 bf16x8 __attribute__((ext_vector_type(8)));
typedef float  f32x4  __attribute__((ext_vector_type(4)));
typedef float  f32x2  __attribute__((ext_vector_type(2)));
typedef unsigned short ushort_t;
typedef unsigned short ushort8 __attribute__((ext_vector_type(8)));

// Problem constants (fixed by the reference).
constexpr int Nn = 50000;   // nodes
constexpr int Ee = 800000;  // edges
constexpr int Dd = 128;     // feature dim
constexpr int Gg = 64;      // graphs
constexpr float SCALE = 0.08838834764831845f; // 1/sqrt(128)

__device__ inline ushort_t f2bf(float f) {
    unsigned u = __float_as_uint(f);
    unsigned r = (u + 0x7FFF + ((u >> 16) & 1)) >> 16;   // RNE truncate to bf16
    return (ushort_t)r;
}
__device__ inline float bf2f(ushort_t b) { return __uint_as_float(((unsigned)b) << 16); }

// 4 packed fp8 (e4m3) -> 4 floats via HW packed converts
__device__ inline void fp8x4_to_f32(int w, float* out) {
    f32x2 lo = __builtin_amdgcn_cvt_pk_f32_fp8(w, false);
    f32x2 hi = __builtin_amdgcn_cvt_pk_f32_fp8(w, true);
    out[0] = lo[0]; out[1] = lo[1]; out[2] = hi[0]; out[3] = hi[1];
}

// ---------------- fused prep: hist(+rank) + graph bounds + convw + convx ----
// hist's atomic return value IS the edge's rank within its destination ->
// scatter later needs no atomics (R15 lesson: scatter atomics + merged-CFG
// regalloc cost the fused gemm ~19us).

constexpr int EB  = (Ee + 255) / 256;   // 3125 hist blocks
constexpr int NBD = (Nn + 255) / 256;   // 196 bound blocks
constexpr int CWB = 64;                 // convw blocks
constexpr int N4  = Nn * Dd / 4;        // 1.6M float4s
constexpr int CXB = N4 / 256;           // 6250 convx blocks

__global__ __launch_bounds__(256) void prep_kernel(
    const int* __restrict__ dst, int* __restrict__ counts, int* __restrict__ rank,
    const int* __restrict__ batch, int* __restrict__ startg, int* __restrict__ endg,
    const float* w0, const float* w1, const float* w2, const float* w3,
    const float* w4, const float* w5, const float* w6, const float* w7,
    ushort_t* __restrict__ Wfh, ushort_t* __restrict__ Wfl,
    const float* __restrict__ x, ushort_t* __restrict__ Xh, ushort_t* __restrict__ Xl) {
    int b = blockIdx.x;
    if (b < EB) {                                   // ---- histogram + rank
        int e = b * 256 + threadIdx.x;
        if (e < Ee) rank[e] = atomicAdd(&counts[dst[e]], 1);
    } else if (b < EB + NBD) {                      // ---- graph bounds
        int n = (b - EB) * 256 + threadIdx.x;
        if (n >= Nn) return;
        int g = batch[n];
        if (n == Nn - 1 || batch[n + 1] != g) endg[g] = n + 1;
        if (n == 0 || batch[n - 1] != g) startg[g] = n;
    } else if (b < EB + NBD + CWB) {                // ---- fragment-order weights
        const float* ws[8] = {w0, w1, w2, w3, w4, w5, w6, w7};
        int b2 = b - (EB + NBD);
        int m = b2 >> 3;
        int tt = (b2 & 7) * 256 + threadIdx.x;      // 0..2047 fragment slots
        int lane = tt & 63;
        int ln = lane & 15, quad = lane >> 4;
        int n = (tt >> 9) * 32 + ((tt >> 8) & 1) * 16 + ln;
        int k0 = ((tt >> 6) & 3) * 32 + quad * 8;
        const float* srcp = ws[m] + n * 128 + k0;
        float4 a = *(const float4*)(srcp);
        float4 bb = *(const float4*)(srcp + 4);
        float e[8] = {a.x, a.y, a.z, a.w, bb.x, bb.y, bb.z, bb.w};
        ushort8 h, l;
#pragma unroll
        for (int j = 0; j < 8; ++j) {
            h[j] = f2bf(e[j]);
            l[j] = f2bf(e[j] - bf2f(h[j]));
        }
        size_t o = (size_t)m * 16384 + (size_t)tt * 8;
        *(ushort8*)(Wfh + o) = h;
        *(ushort8*)(Wfl + o) = l;
    } else {                                        // ---- split-bf16 convx
        int i = (b - (EB + NBD + CWB)) * 256 + threadIdx.x;
        if (i >= N4) return;
        float4 xv = ((const float4*)x)[i];
        ushort4 h, l;
        h.x = f2bf(xv.x); l.x = f2bf(xv.x - bf2f(h.x));
        h.y = f2bf(xv.y); l.y = f2bf(xv.y - bf2f(h.y));
        h.z = f2bf(xv.z); l.z = f2bf(xv.z - bf2f(h.z));
        h.w = f2bf(xv.w); l.w = f2bf(xv.w - bf2f(h.w));
        ((ushort4*)Xh)[i] = h;
        ((ushort4*)Xl)[i] = l;
    }
}

// ---------------- scans (CSR offsets) ----------------

__global__ __launch_bounds__(256) void scan1_kernel(const int* __restrict__ counts,
                                                    int* __restrict__ offsets,
                                                    int* __restrict__ blockSums) {
    __shared__ int sh[256];
    int i = blockIdx.x * 256 + threadIdx.x;
    int v = (i < Nn) ? counts[i] : 0;
    sh[threadIdx.x] = v;
    __syncthreads();
    for (int off = 1; off < 256; off <<= 1) {
        int t = (threadIdx.x >= off) ? sh[threadIdx.x - off] : 0;
        __syncthreads();
        sh[threadIdx.x] += t;
        __syncthreads();
    }
    if (i < Nn) offsets[i] = sh[threadIdx.x] - v;   // exclusive within block
    if (threadIdx.x == 255) blockSums[blockIdx.x] = sh[255];
}

__global__ __launch_bounds__(256) void scan2_kernel(int* __restrict__ blockSums, int nb) {
    __shared__ int sh[256];
    int t = threadIdx.x;
    int v = (t < nb) ? blockSums[t] : 0;
    sh[t] = v;
    __syncthreads();
    for (int off = 1; off < 256; off <<= 1) {
        int u = (t >= off) ? sh[t - off] : 0;
        __syncthreads();
        sh[t] += u;
        __syncthreads();
    }
    if (t < nb) blockSums[t] = sh[t] - v;           // exclusive across blocks
}

__global__ __launch_bounds__(256) void scan3_kernel(int* __restrict__ offsets,
                                                    const int* __restrict__ blockSums) {
    int i = blockIdx.x * 256 + threadIdx.x;
    if (i < Nn) offsets[i] += blockSums[blockIdx.x];
    if (i == 0) offsets[Nn] = Ee;
}

// ---------------- MFMA split-bf16 GEMM body: Y = X @ W^T + b ----------------
// LDS-staged X (coalesced 4KB loads), fragment-order weights.
// q,s out bf16; k,v out FP8-e4m3 interleaved in kv (row = 256B [k|v]).

constexpr int XS = 136;   // LDS row stride in shorts (pad -> bank rotate)

__device__ __attribute__((always_inline)) void gemm_body(int bx, int which,
    const ushort_t* __restrict__ Xh, const ushort_t* __restrict__ Xl,
    const ushort_t* __restrict__ Wfh, const ushort_t* __restrict__ Wfl,
    int lw,
    const float* __restrict__ b0, const float* __restrict__ b1,
    const float* __restrict__ b2, const float* __restrict__ b3,
    ushort_t* __restrict__ Oq, char* __restrict__ Okv,
    ushort_t* __restrict__ Os) {
    __shared__ ushort_t XhS[64 * XS];
    __shared__ ushort_t XlS[64 * XS];
    const ushort_t* wfh = Wfh + (size_t)(lw + which) * 16384;
    const ushort_t* wfl = Wfl + (size_t)(lw + which) * 16384;
    const float* bias = (which == 0) ? b0 : (which == 1) ? b1 : (which == 2) ? b2 : b3;
    bool isfp8 = (which == 1 || which == 2);
    char*     Okv8 = Okv + ((which == 2) ? 128 : 0);     // fp8, row stride 256B
    ushort_t* Obf  = (which == 0) ? Oq : Os;             // bf16, row stride 128

    int w = threadIdx.x >> 6;
    int lane = threadIdx.x & 63;
    int quad = lane >> 4, ln = lane & 15;
    int n0 = w * 32;

    bf16x8 bh[2][4], bl[2][4];
#pragma unroll
    for (int ct = 0; ct < 2; ++ct)
#pragma unroll
        for (int kc = 0; kc < 4; ++kc) {
            int off = (w * 512 + ct * 256 + kc * 64 + lane) * 8;
            bh[ct][kc] = *(const bf16x8*)(wfh + off);
            bl[ct][kc] = *(const bf16x8*)(wfl + off);
        }
    float bias0 = bias[n0 + ln];
    float bias1 = bias[n0 + 16 + ln];

    int rowBase = bx * 256;
    int trow = threadIdx.x >> 4;          // staging: 16 rows per instruction
    int tcol = (threadIdx.x & 15) * 8;    // 16B per lane, contiguous per row

    for (int chunk = 0; chunk < 4; ++chunk) {
        int cbase = rowBase + chunk * 64;
        __syncthreads();
#pragma unroll
        for (int rr = 0; rr < 4; ++rr) {
            int lrow = trow + rr * 16;
            int grow = min(cbase + lrow, Nn - 1);
            *(ushort8*)(&XhS[lrow * XS + tcol]) =
                *(const ushort8*)(Xh + (size_t)grow * 128 + tcol);
            *(ushort8*)(&XlS[lrow * XS + tcol]) =
                *(const ushort8*)(Xl + (size_t)grow * 128 + tcol);
        }
        __syncthreads();

#pragma unroll
        for (int rt = 0; rt < 4; ++rt) {
            const ushort_t* ph = &XhS[(rt * 16 + ln) * XS + quad * 8];
            const ushort_t* pl = &XlS[(rt * 16 + ln) * XS + quad * 8];
            bf16x8 ah[4], al[4];
#pragma unroll
            for (int kc = 0; kc < 4; ++kc) {
                ah[kc] = *(const bf16x8*)(ph + kc * 32);
                al[kc] = *(const bf16x8*)(pl + kc * 32);
            }
            f32x4 acc00 = {0.f,0.f,0.f,0.f}, acc01 = {0.f,0.f,0.f,0.f};
            f32x4 acc10 = {0.f,0.f,0.f,0.f}, acc11 = {0.f,0.f,0.f,0.f};
#pragma unroll
            for (int kc = 0; kc < 2; ++kc) {
                int k2 = kc + 2;
                acc00 = __builtin_amdgcn_mfma_f32_16x16x32_bf16(ah[kc], bh[0][kc], acc00, 0, 0, 0);
                acc01 = __builtin_amdgcn_mfma_f32_16x16x32_bf16(ah[kc], bh[1][kc], acc01, 0, 0, 0);
                acc10 = __builtin_amdgcn_mfma_f32_16x16x32_bf16(ah[k2], bh[0][k2], acc10, 0, 0, 0);
                acc11 = __builtin_amdgcn_mfma_f32_16x16x32_bf16(ah[k2], bh[1][k2], acc11, 0, 0, 0);
                acc00 = __builtin_amdgcn_mfma_f32_16x16x32_bf16(ah[kc], bl[0][kc], acc00, 0, 0, 0);
                acc01 = __builtin_amdgcn_mfma_f32_16x16x32_bf16(ah[kc], bl[1][kc], acc01, 0, 0, 0);
                acc10 = __builtin_amdgcn_mfma_f32_16x16x32_bf16(ah[k2], bl[0][k2], acc10, 0, 0, 0);
                acc11 = __builtin_amdgcn_mfma_f32_16x16x32_bf16(ah[k2], bl[1][k2], acc11, 0, 0, 0);
                acc00 = __builtin_amdgcn_mfma_f32_16x16x32_bf16(al[kc], bh[0][kc], acc00, 0, 0, 0);
                acc01 = __builtin_amdgcn_mfma_f32_16x16x32_bf16(al[kc], bh[1][kc], acc01, 0, 0, 0);
                acc10 = __builtin_amdgcn_mfma_f32_16x16x32_bf16(al[k2], bh[0][k2], acc10, 0, 0, 0);
                acc11 = __builtin_amdgcn_mfma_f32_16x16x32_bf16(al[k2], bh[1][k2], acc11, 0, 0, 0);
            }
            int m0 = cbase + rt * 16;
            int orow0 = m0 + quad * 4;
            bool full = (orow0 + 3) < Nn;
#pragma unroll
            for (int reg = 0; reg < 4; ++reg) {
                int orow = orow0 + reg;
                if (full || orow < Nn) {
                    float o0 = acc00[reg] + acc10[reg] + bias0;
                    float o1 = acc01[reg] + acc11[reg] + bias1;
                    if (isfp8) {
                        int pk = __builtin_amdgcn_cvt_pk_fp8_f32(o0, o1, 0, false);
                        size_t ob = (size_t)orow * 256;
                        Okv8[ob + n0 + ln]      = (char)(pk & 0xff);
                        Okv8[ob + n0 + 16 + ln] = (char)((pk >> 8) & 0xff);
                    } else {
                        size_t ob = (size_t)orow * 128;
                        Obf[ob + n0 + ln]      = f2bf(o0);
                        Obf[ob + n0 + 16 + ln] = f2bf(o1);
                    }
                }
            }
        }
    }
}

// layer-1 gemm (2D grid, plain)
__global__ __launch_bounds__(256) void gemm_mfma_kernel(
    const ushort_t* __restrict__ Xh, const ushort_t* __restrict__ Xl,
    const ushort_t* __restrict__ Wfh, const ushort_t* __restrict__ Wfl,
    int lw,
    const float* __restrict__ b0, const float* __restrict__ b1,
    const float* __restrict__ b2, const float* __restrict__ b3,
    ushort_t* __restrict__ Oq, char* __restrict__ Okv,
    ushort_t* __restrict__ Os) {
    gemm_body(blockIdx.x, blockIdx.y, Xh, Xl, Wfh, Wfl, lw, b0, b1, b2, b3, Oq, Okv, Os);
}

// layer-0 gemm fused with ATOMIC-FREE edge scatter (rank precomputed in prep;
// scatter branch early-returns so regalloc doesn't tax the gemm path).
constexpr int G0B = 196 * 4;

__global__ __launch_bounds__(256) void gemm0_scatter_kernel(
    const ushort_t* __restrict__ Xh, const ushort_t* __restrict__ Xl,
    const ushort_t* __restrict__ Wfh, const ushort_t* __restrict__ Wfl,
    const float* __restrict__ b0, const float* __restrict__ b1,
    const float* __restrict__ b2, const float* __restrict__ b3,
    ushort_t* __restrict__ Oq, char* __restrict__ Okv, ushort_t* __restrict__ Os,
    const int* __restrict__ src, const int* __restrict__ dst,
    const int* __restrict__ offsets, const int* __restrict__ rank,
    int* __restrict__ sorted_src) {
    int b = blockIdx.x;
    if (b >= G0B) {
        int e = (b - G0B) * 256 + threadIdx.x;
        if (e < Ee) sorted_src[offsets[dst[e]] + rank[e]] = src[e];
        return;
    }
    gemm_body(b % 196, b / 196, Xh, Xl, Wfh, Wfl, 0, b0, b1, b2, b3, Oq, Okv, Os);
}

// ---------------- fused per-node attention (single pass, fp8 kv) ------------
// R11 body verbatim — verified best (R12/R13/R14 variants all regressed).
// alpha bounded -> no max subtraction. 8 groups x 8 lanes; lane owns dims
// [gl*16,+16); each edge reads ONE contiguous 256B fp8 kv block.

__global__ __launch_bounds__(256) void attn_kernel(const ushort_t* __restrict__ q,
                                                   const char* __restrict__ kv,
                                                   const ushort_t* __restrict__ s,
                                                   const int* __restrict__ offsets,
                                                   const int* __restrict__ sorted_src,
                                                   ushort_t* __restrict__ oh,
                                                   ushort_t* __restrict__ ol,
                                                   int write_split) {
    int wid = blockIdx.x * 4 + (threadIdx.x >> 6);
    if (wid >= Nn) return;
    int lane = threadIdx.x & 63;
    int g = lane >> 3;           // edge parity group 0..7
    int gl = lane & 7;           // dim chunk: [gl*16, gl*16+16)
    const ushort_t* qp = q + (size_t)wid * 128 + gl * 16;
    ushort8 qa = *(const ushort8*)(qp);
    ushort8 qb = *(const ushort8*)(qp + 8);
    float qf[16];
#pragma unroll
    for (int j = 0; j < 8; ++j) { qf[j] = bf2f(qa[j]); qf[j + 8] = bf2f(qb[j]); }
    int beg = offsets[wid], end = offsets[wid + 1];

    float l = 0.f;
    float acc[16];
#pragma unroll
    for (int j = 0; j < 16; ++j) acc[j] = 0.f;

    for (int e = beg + g; e < end; e += 8) {
        int sidx = sorted_src[e];
        const char* kvp = kv + (size_t)sidx * 256 + gl * 16;
        int4 kw = *(const int4*)(kvp);
        int4 vw = *(const int4*)(kvp + 128);
        float kf[16], vf[16];
        fp8x4_to_f32(kw.x, kf);      fp8x4_to_f32(kw.y, kf + 4);
        fp8x4_to_f32(kw.z, kf + 8);  fp8x4_to_f32(kw.w, kf + 12);
        float part = 0.f;
#pragma unroll
        for (int j = 0; j < 16; ++j) part += qf[j] * kf[j];
        part += __shfl_xor(part, 1, 64);
        part += __shfl_xor(part, 2, 64);
        part += __shfl_xor(part, 4, 64);
        float pw = __expf(part * SCALE);
        l += pw;
        fp8x4_to_f32(vw.x, vf);      fp8x4_to_f32(vw.y, vf + 4);
        fp8x4_to_f32(vw.z, vf + 8);  fp8x4_to_f32(vw.w, vf + 12);
#pragma unroll
        for (int j = 0; j < 16; ++j) acc[j] += pw * vf[j];
    }

    // plain-sum merge across the 8 groups (same gl holds same dims)
#pragma unroll
    for (int off = 8; off <= 32; off <<= 1) {
        l += __shfl_xor(l, off, 64);
#pragma unroll
        for (int j = 0; j < 16; ++j) acc[j] += __shfl_xor(acc[j], off, 64);
    }

    if (g == 0) {
        float inv = (l > 0.f) ? (1.0f / l) : 0.f;   // deg==0 -> pure skip
        const ushort_t* sp = s + (size_t)wid * 128 + gl * 16;
        ushort8 sa = *(const ushort8*)(sp);
        ushort8 sb = *(const ushort8*)(sp + 8);
        float ov[16];
#pragma unroll
        for (int j = 0; j < 8; ++j) {
            ov[j]     = fmaxf(acc[j] * inv + bf2f(sa[j]), 0.f);
            ov[j + 8] = fmaxf(acc[j + 8] * inv + bf2f(sb[j]), 0.f);
        }
        if (write_split) {
            ushort8 h0, h1, l0, l1;
#pragma unroll
            for (int j = 0; j < 8; ++j) {
                h0[j] = f2bf(ov[j]);     l0[j] = f2bf(ov[j] - bf2f(h0[j]));
                h1[j] = f2bf(ov[j + 8]); l1[j] = f2bf(ov[j + 8] - bf2f(h1[j]));
            }
            ushort_t* op = oh + (size_t)wid * 128 + gl * 16;
            ushort_t* lp = ol + (size_t)wid * 128 + gl * 16;
            *(ushort8*)(op)     = h0;
            *(ushort8*)(op + 8) = h1;
            *(ushort8*)(lp)     = l0;
            *(ushort8*)(lp + 8) = l1;
        } else {
            ushort8 h0, h1;
#pragma unroll
            for (int j = 0; j < 8; ++j) { h0[j] = f2bf(ov[j]); h1[j] = f2bf(ov[j + 8]); }
            ushort_t* op = oh + (size_t)wid * 128 + gl * 16;
            *(ushort8*)(op)     = h0;
            *(ushort8*)(op + 8) = h1;
        }
    }
}

// ---------------- pooling (bf16 h, coalesced rows, LDS partials) ----------------

__global__ __launch_bounds__(256) void pool_kernel(const ushort_t* __restrict__ hb,
                                                   const int* __restrict__ batch,
                                                   float* __restrict__ pooled) {
    __shared__ float ps[4][128];
    int n0 = blockIdx.x * 256;
    int t = threadIdx.x;
    int lane32 = t & 31, rowgrp = t >> 5;
    for (int i = t; i < 512; i += 256) ((float*)ps)[i] = 0.f;
    __syncthreads();
    int gfirst = batch[min(n0, Nn - 1)];
    int d0 = lane32 * 4;
    float a0 = 0.f, a1 = 0.f, a2 = 0.f, a3 = 0.f;
    int curg = -1;
    for (int rr = 0; rr < 32; ++rr) {
        int n = n0 + rowgrp + rr * 8;
        if (n >= Nn) break;
        int g = batch[n];
        if (g != curg) {
            if (curg >= 0) {
                int slot = curg - gfirst;
                if (slot < 4) {
                    atomicAdd(&ps[slot][d0],     a0);
                    atomicAdd(&ps[slot][d0 + 1], a1);
                    atomicAdd(&ps[slot][d0 + 2], a2);
                    atomicAdd(&ps[slot][d0 + 3], a3);
                } else {
                    atomicAdd(&pooled[curg * Dd + d0],     a0);
                    atomicAdd(&pooled[curg * Dd + d0 + 1], a1);
                    atomicAdd(&pooled[curg * Dd + d0 + 2], a2);
                    atomicAdd(&pooled[curg * Dd + d0 + 3], a3);
                }
                a0 = a1 = a2 = a3 = 0.f;
            }
            curg = g;
        }
        ushort4 hv = *(const ushort4*)(hb + (size_t)n * 128 + d0);
        a0 += bf2f(hv.x); a1 += bf2f(hv.y); a2 += bf2f(hv.z); a3 += bf2f(hv.w);
    }
    if (curg >= 0) {
        int slot = curg - gfirst;
        if (slot < 4) {
            atomicAdd(&ps[slot][d0],     a0);
            atomicAdd(&ps[slot][d0 + 1], a1);
            atomicAdd(&ps[slot][d0 + 2], a2);
            atomicAdd(&ps[slot][d0 + 3], a3);
        } else {
            atomicAdd(&pooled[curg * Dd + d0],     a0);
            atomicAdd(&pooled[curg * Dd + d0 + 1], a1);
            atomicAdd(&pooled[curg * Dd + d0 + 2], a2);
            atomicAdd(&pooled[curg * Dd + d0 + 3], a3);
        }
    }
    __syncthreads();
    int glast = batch[min(n0 + 255, Nn - 1)];
    int nslots = min(glast - gfirst + 1, 4);
    for (int i = t; i < nslots * 128; i += 256) {
        int slot = i >> 7, d = i & 127;
        atomicAdd(&pooled[(gfirst + slot) * Dd + d], ps[slot][d]);
    }
}

__global__ __launch_bounds__(64) void mlp_kernel(const float* __restrict__ pooled,
                                                 const int* __restrict__ startg,
                                                 const int* __restrict__ endg,
                                                 const float* __restrict__ Wc1,
                                                 const float* __restrict__ bc1,
                                                 const float* __restrict__ Wc2,
                                                 const float* __restrict__ bc2,
                                                 float* __restrict__ out) {
    __shared__ float pm[128];
    __shared__ float hid[64];
    int g = blockIdx.x, t = threadIdx.x;   // 64 threads
    float cnt = fmaxf((float)(endg[g] - startg[g]), 1.0f);
    float invc = 1.0f / cnt;
    pm[t]      = pooled[g * 128 + t] * invc;
    pm[t + 64] = pooled[g * 128 + 64 + t] * invc;
    __syncthreads();
    float acc = bc1[t];
    for (int i = 0; i < 128; ++i) acc += pm[i] * Wc1[t * 128 + i];
    hid[t] = fmaxf(acc, 0.f);
    __syncthreads();
    if (t < 2) {
        float a = bc2[t];
        for (int i = 0; i < 64; ++i) a += hid[i] * Wc2[t * 64 + i];
        out[g * 2 + t] = a;
    }
}

// ---------------- launch ----------------

extern "C" void kernel_launch(void* const* d_in, const int* in_sizes, int n_in,
                              void* d_out, int out_size, void* d_ws, size_t ws_size,
                              hipStream_t stream) {
    const float* x   = (const float*)d_in[0];
    const int*   ei  = (const int*)d_in[1];
    const int* batch = (const int*)d_in[2];
    const float* W[2][4];
    const float* B[2][4];
    for (int l = 0; l < 2; ++l) {
        for (int j = 0; j < 4; ++j) W[l][j] = (const float*)d_in[3 + l * 8 + j];
        for (int j = 0; j < 4; ++j) B[l][j] = (const float*)d_in[3 + l * 8 + 4 + j];
    }
    const float* Wc1 = (const float*)d_in[19];
    const float* bc1 = (const float*)d_in[20];
    const float* Wc2 = (const float*)d_in[21];
    const float* bc2 = (const float*)d_in[22];
    float* out = (float*)d_out;

    const int* src = ei;        // edge_index[0]
    const int* dst = ei + Ee;   // edge_index[1]

    char* p = (char*)d_ws;
    auto alloc = [&](size_t bytes) {
        void* r = (void*)p;
        p += (bytes + 255) & ~(size_t)255;
        return r;
    };
    ushort_t* q  = (ushort_t*)alloc((size_t)Nn * 128 * 2);  // bf16
    char*     kv = (char*)alloc((size_t)Nn * 256);          // fp8 [k_row|v_row]
    ushort_t* ss = (ushort_t*)alloc((size_t)Nn * 128 * 2);  // bf16
    ushort_t* hb = (ushort_t*)alloc((size_t)Nn * 128 * 2);  // bf16 layer-2 h
    ushort_t* Xh = (ushort_t*)alloc((size_t)Nn * 128 * 2);
    ushort_t* Xl = (ushort_t*)alloc((size_t)Nn * 128 * 2);
    ushort_t* Wfh = (ushort_t*)alloc((size_t)8 * 16384 * 2);
    ushort_t* Wfl = (ushort_t*)alloc((size_t)8 * 16384 * 2);
    char* zbase = p;  // region zeroed each launch
    int*   counts = (int*)alloc(Nn * 4);
    int*   startg = (int*)alloc(Gg * 4);
    int*   endg   = (int*)alloc(Gg * 4);
    float* pooled = (float*)alloc(Gg * Dd * 4);
    size_t zbytes = (size_t)(p - zbase);
    int* offsets    = (int*)alloc((size_t)(Nn + 1) * 4);
    int* rank       = (int*)alloc((size_t)Ee * 4);
    int* blockSums  = (int*)alloc(256 * 4);
    int* sorted_src = (int*)alloc((size_t)Ee * 4);

    hipMemsetAsync(zbase, 0, zbytes, stream);

    constexpr int NB = (Nn + 255) / 256;  // 196 scan blocks

    // prep: hist(+rank) + bounds + convw + convx (independent, one launch)
    prep_kernel<<<EB + NBD + CWB + CXB, 256, 0, stream>>>(
        dst, counts, rank, batch, startg, endg,
        W[0][0], W[0][1], W[0][2], W[0][3], W[1][0], W[1][1], W[1][2], W[1][3],
        Wfh, Wfl, x, Xh, Xl);
    scan1_kernel<<<NB, 256, 0, stream>>>(counts, offsets, blockSums);
    scan2_kernel<<<1, 256, 0, stream>>>(blockSums, NB);
    scan3_kernel<<<NB, 256, 0, stream>>>(offsets, blockSums);

    // layer-0 gemm fused with atomic-free scatter
    gemm0_scatter_kernel<<<G0B + EB, 256, 0, stream>>>(
        Xh, Xl, Wfh, Wfl, B[0][0], B[0][1], B[0][2], B[0][3],
        q, kv, ss, src, dst, offsets, rank, sorted_src);

    // layer-0 attn writes split-bf16 h straight into Xh/Xl
    attn_kernel<<<(Nn + 3) / 4, 256, 0, stream>>>(q, kv, ss, offsets, sorted_src,
                                                  Xh, Xl, 1);
    // layer 1
    dim3 ggrid(196, 4);
    gemm_mfma_kernel<<<ggrid, 256, 0, stream>>>(Xh, Xl, Wfh, Wfl, 4,
                                                B[1][0], B[1][1], B[1][2], B[1][3],
                                                q, kv, ss);
    attn_kernel<<<(Nn + 3) / 4, 256, 0, stream>>>(q, kv, ss, offsets, sorted_src,
                                                  hb, hb, 0);

    pool_kernel<<<(Nn + 255) / 256, 256, 0, stream>>>(hb, batch, pooled);
    mlp_kernel<<<Gg, 64, 0, stream>>>(pooled, startg, endg, Wc1, bc1, Wc2, bc2, out);
}

// Round 17
// 331.626 us; speedup vs baseline: 1.2263x; 1.0283x over previous
//
#include <hip/hip_runtime.h>
#include <math.h>

typedef __bf16 bf16x8 __attribute__((ext_vector_type(8)));
typedef float  f32x4  __attribute__((ext_vector_type(4)));
typedef float  f32x2  __attribute__((ext_vector_type(2)));
typedef unsigned short ushort_t;
typedef unsigned short ushort8 __attribute__((ext_vector_type(8)));

// Problem constants (fixed by the reference).
constexpr int Nn = 50000;   // nodes
constexpr int Ee = 800000;  // edges
constexpr int Dd = 128;     // feature dim
constexpr int Gg = 64;      // graphs
constexpr float SCALE = 0.08838834764831845f; // 1/sqrt(128)
constexpr float QS    = 16.0f;                 // int8 quant scale for q,k
constexpr float ISC   = SCALE / (QS * QS);     // int-dot -> alpha

__device__ inline ushort_t f2bf(float f) {
    unsigned u = __float_as_uint(f);
    unsigned r = (u + 0x7FFF + ((u >> 16) & 1)) >> 16;   // RNE truncate to bf16
    return (ushort_t)r;
}
__device__ inline float bf2f(ushort_t b) { return __uint_as_float(((unsigned)b) << 16); }

__device__ inline char q_i8(float f) {
    int v = (int)rintf(f * QS);
    v = max(-127, min(127, v));
    return (char)v;
}

// 4 packed fp8 (e4m3) -> 4 floats via HW packed converts
__device__ inline void fp8x4_to_f32(int w, float* out) {
    f32x2 lo = __builtin_amdgcn_cvt_pk_f32_fp8(w, false);
    f32x2 hi = __builtin_amdgcn_cvt_pk_f32_fp8(w, true);
    out[0] = lo[0]; out[1] = lo[1]; out[2] = hi[0]; out[3] = hi[1];
}

// ---------------- fused prep: hist(+rank) + graph bounds + convw + convx ----

constexpr int EB  = (Ee + 255) / 256;   // 3125 hist blocks
constexpr int NBD = (Nn + 255) / 256;   // 196 bound blocks
constexpr int CWB = 64;                 // convw blocks
constexpr int N4  = Nn * Dd / 4;        // 1.6M float4s
constexpr int CXB = N4 / 256;           // 6250 convx blocks

__global__ __launch_bounds__(256) void prep_kernel(
    const int* __restrict__ dst, int* __restrict__ counts, int* __restrict__ rank,
    const int* __restrict__ batch, int* __restrict__ startg, int* __restrict__ endg,
    const float* w0, const float* w1, const float* w2, const float* w3,
    const float* w4, const float* w5, const float* w6, const float* w7,
    ushort_t* __restrict__ Wfh, ushort_t* __restrict__ Wfl,
    const float* __restrict__ x, ushort_t* __restrict__ Xh, ushort_t* __restrict__ Xl) {
    int b = blockIdx.x;
    if (b < EB) {                                   // ---- histogram + rank
        int e = b * 256 + threadIdx.x;
        if (e < Ee) rank[e] = atomicAdd(&counts[dst[e]], 1);
    } else if (b < EB + NBD) {                      // ---- graph bounds
        int n = (b - EB) * 256 + threadIdx.x;
        if (n >= Nn) return;
        int g = batch[n];
        if (n == Nn - 1 || batch[n + 1] != g) endg[g] = n + 1;
        if (n == 0 || batch[n - 1] != g) startg[g] = n;
    } else if (b < EB + NBD + CWB) {                // ---- fragment-order weights
        const float* ws[8] = {w0, w1, w2, w3, w4, w5, w6, w7};
        int b2 = b - (EB + NBD);
        int m = b2 >> 3;
        int tt = (b2 & 7) * 256 + threadIdx.x;      // 0..2047 fragment slots
        int lane = tt & 63;
        int ln = lane & 15, quad = lane >> 4;
        int n = (tt >> 9) * 32 + ((tt >> 8) & 1) * 16 + ln;
        int k0 = ((tt >> 6) & 3) * 32 + quad * 8;
        const float* srcp = ws[m] + n * 128 + k0;
        float4 a = *(const float4*)(srcp);
        float4 bb = *(const float4*)(srcp + 4);
        float e[8] = {a.x, a.y, a.z, a.w, bb.x, bb.y, bb.z, bb.w};
        ushort8 h, l;
#pragma unroll
        for (int j = 0; j < 8; ++j) {
            h[j] = f2bf(e[j]);
            l[j] = f2bf(e[j] - bf2f(h[j]));
        }
        size_t o = (size_t)m * 16384 + (size_t)tt * 8;
        *(ushort8*)(Wfh + o) = h;
        *(ushort8*)(Wfl + o) = l;
    } else {                                        // ---- split-bf16 convx
        int i = (b - (EB + NBD + CWB)) * 256 + threadIdx.x;
        if (i >= N4) return;
        float4 xv = ((const float4*)x)[i];
        ushort4 h, l;
        h.x = f2bf(xv.x); l.x = f2bf(xv.x - bf2f(h.x));
        h.y = f2bf(xv.y); l.y = f2bf(xv.y - bf2f(h.y));
        h.z = f2bf(xv.z); l.z = f2bf(xv.z - bf2f(h.z));
        h.w = f2bf(xv.w); l.w = f2bf(xv.w - bf2f(h.w));
        ((ushort4*)Xh)[i] = h;
        ((ushort4*)Xl)[i] = l;
    }
}

// ---------------- scans (CSR offsets) ----------------

__global__ __launch_bounds__(256) void scan1_kernel(const int* __restrict__ counts,
                                                    int* __restrict__ offsets,
                                                    int* __restrict__ blockSums) {
    __shared__ int sh[256];
    int i = blockIdx.x * 256 + threadIdx.x;
    int v = (i < Nn) ? counts[i] : 0;
    sh[threadIdx.x] = v;
    __syncthreads();
    for (int off = 1; off < 256; off <<= 1) {
        int t = (threadIdx.x >= off) ? sh[threadIdx.x - off] : 0;
        __syncthreads();
        sh[threadIdx.x] += t;
        __syncthreads();
    }
    if (i < Nn) offsets[i] = sh[threadIdx.x] - v;   // exclusive within block
    if (threadIdx.x == 255) blockSums[blockIdx.x] = sh[255];
}

__global__ __launch_bounds__(256) void scan2_kernel(int* __restrict__ blockSums, int nb) {
    __shared__ int sh[256];
    int t = threadIdx.x;
    int v = (t < nb) ? blockSums[t] : 0;
    sh[t] = v;
    __syncthreads();
    for (int off = 1; off < 256; off <<= 1) {
        int u = (t >= off) ? sh[t - off] : 0;
        __syncthreads();
        sh[t] += u;
        __syncthreads();
    }
    if (t < nb) blockSums[t] = sh[t] - v;           // exclusive across blocks
}

__global__ __launch_bounds__(256) void scan3_kernel(int* __restrict__ offsets,
                                                    const int* __restrict__ blockSums) {
    int i = blockIdx.x * 256 + threadIdx.x;
    if (i < Nn) offsets[i] += blockSums[blockIdx.x];
    if (i == 0) offsets[Nn] = Ee;
}

// ---------------- MFMA split-bf16 GEMM body: Y = X @ W^T + b ----------------
// LDS-staged X (coalesced 4KB loads), fragment-order weights.
// q,k out INT8 (scale 16); v out FP8-e4m3; s out bf16.
// kv row = 256B [k_int8(128B) | v_fp8(128B)]; q row = 128B int8.

constexpr int XS = 136;   // LDS row stride in shorts (pad -> bank rotate)

__device__ __attribute__((always_inline)) void gemm_body(int bx, int which,
    const ushort_t* __restrict__ Xh, const ushort_t* __restrict__ Xl,
    const ushort_t* __restrict__ Wfh, const ushort_t* __restrict__ Wfl,
    int lw,
    const float* __restrict__ b0, const float* __restrict__ b1,
    const float* __restrict__ b2, const float* __restrict__ b3,
    char* __restrict__ Oq, char* __restrict__ Okv,
    ushort_t* __restrict__ Os) {
    __shared__ ushort_t XhS[64 * XS];
    __shared__ ushort_t XlS[64 * XS];
    const ushort_t* wfh = Wfh + (size_t)(lw + which) * 16384;
    const ushort_t* wfl = Wfl + (size_t)(lw + which) * 16384;
    const float* bias = (which == 0) ? b0 : (which == 1) ? b1 : (which == 2) ? b2 : b3;
    // output routing: 0=q int8(128B rows) 1=k int8(kv+0) 2=v fp8(kv+128) 3=s bf16
    char* O8 = (which == 0) ? Oq : (which == 1) ? Okv : Okv + 128;
    int   o8str = (which == 0) ? 128 : 256;

    int w = threadIdx.x >> 6;
    int lane = threadIdx.x & 63;
    int quad = lane >> 4, ln = lane & 15;
    int n0 = w * 32;

    bf16x8 bh[2][4], bl[2][4];
#pragma unroll
    for (int ct = 0; ct < 2; ++ct)
#pragma unroll
        for (int kc = 0; kc < 4; ++kc) {
            int off = (w * 512 + ct * 256 + kc * 64 + lane) * 8;
            bh[ct][kc] = *(const bf16x8*)(wfh + off);
            bl[ct][kc] = *(const bf16x8*)(wfl + off);
        }
    float bias0 = bias[n0 + ln];
    float bias1 = bias[n0 + 16 + ln];

    int rowBase = bx * 256;
    int trow = threadIdx.x >> 4;          // staging: 16 rows per instruction
    int tcol = (threadIdx.x & 15) * 8;    // 16B per lane, contiguous per row

    for (int chunk = 0; chunk < 4; ++chunk) {
        int cbase = rowBase + chunk * 64;
        __syncthreads();
#pragma unroll
        for (int rr = 0; rr < 4; ++rr) {
            int lrow = trow + rr * 16;
            int grow = min(cbase + lrow, Nn - 1);
            *(ushort8*)(&XhS[lrow * XS + tcol]) =
                *(const ushort8*)(Xh + (size_t)grow * 128 + tcol);
            *(ushort8*)(&XlS[lrow * XS + tcol]) =
                *(const ushort8*)(Xl + (size_t)grow * 128 + tcol);
        }
        __syncthreads();

#pragma unroll
        for (int rt = 0; rt < 4; ++rt) {
            const ushort_t* ph = &XhS[(rt * 16 + ln) * XS + quad * 8];
            const ushort_t* pl = &XlS[(rt * 16 + ln) * XS + quad * 8];
            bf16x8 ah[4], al[4];
#pragma unroll
            for (int kc = 0; kc < 4; ++kc) {
                ah[kc] = *(const bf16x8*)(ph + kc * 32);
                al[kc] = *(const bf16x8*)(pl + kc * 32);
            }
            f32x4 acc00 = {0.f,0.f,0.f,0.f}, acc01 = {0.f,0.f,0.f,0.f};
            f32x4 acc10 = {0.f,0.f,0.f,0.f}, acc11 = {0.f,0.f,0.f,0.f};
#pragma unroll
            for (int kc = 0; kc < 2; ++kc) {
                int k2 = kc + 2;
                acc00 = __builtin_amdgcn_mfma_f32_16x16x32_bf16(ah[kc], bh[0][kc], acc00, 0, 0, 0);
                acc01 = __builtin_amdgcn_mfma_f32_16x16x32_bf16(ah[kc], bh[1][kc], acc01, 0, 0, 0);
                acc10 = __builtin_amdgcn_mfma_f32_16x16x32_bf16(ah[k2], bh[0][k2], acc10, 0, 0, 0);
                acc11 = __builtin_amdgcn_mfma_f32_16x16x32_bf16(ah[k2], bh[1][k2], acc11, 0, 0, 0);
                acc00 = __builtin_amdgcn_mfma_f32_16x16x32_bf16(ah[kc], bl[0][kc], acc00, 0, 0, 0);
                acc01 = __builtin_amdgcn_mfma_f32_16x16x32_bf16(ah[kc], bl[1][kc], acc01, 0, 0, 0);
                acc10 = __builtin_amdgcn_mfma_f32_16x16x32_bf16(ah[k2], bl[0][k2], acc10, 0, 0, 0);
                acc11 = __builtin_amdgcn_mfma_f32_16x16x32_bf16(ah[k2], bl[1][k2], acc11, 0, 0, 0);
                acc00 = __builtin_amdgcn_mfma_f32_16x16x32_bf16(al[kc], bh[0][kc], acc00, 0, 0, 0);
                acc01 = __builtin_amdgcn_mfma_f32_16x16x32_bf16(al[kc], bh[1][kc], acc01, 0, 0, 0);
                acc10 = __builtin_amdgcn_mfma_f32_16x16x32_bf16(al[k2], bh[0][k2], acc10, 0, 0, 0);
                acc11 = __builtin_amdgcn_mfma_f32_16x16x32_bf16(al[k2], bh[1][k2], acc11, 0, 0, 0);
            }
            int m0 = cbase + rt * 16;
            int orow0 = m0 + quad * 4;
            bool full = (orow0 + 3) < Nn;
#pragma unroll
            for (int reg = 0; reg < 4; ++reg) {
                int orow = orow0 + reg;
                if (full || orow < Nn) {
                    float o0 = acc00[reg] + acc10[reg] + bias0;
                    float o1 = acc01[reg] + acc11[reg] + bias1;
                    if (which <= 1) {                 // q,k: int8 scale 16
                        size_t ob = (size_t)orow * o8str;
                        O8[ob + n0 + ln]      = q_i8(o0);
                        O8[ob + n0 + 16 + ln] = q_i8(o1);
                    } else if (which == 2) {          // v: fp8
                        int pk = __builtin_amdgcn_cvt_pk_fp8_f32(o0, o1, 0, false);
                        size_t ob = (size_t)orow * 256;
                        O8[ob + n0 + ln]      = (char)(pk & 0xff);
                        O8[ob + n0 + 16 + ln] = (char)((pk >> 8) & 0xff);
                    } else {                          // s: bf16
                        size_t ob = (size_t)orow * 128;
                        Os[ob + n0 + ln]      = f2bf(o0);
                        Os[ob + n0 + 16 + ln] = f2bf(o1);
                    }
                }
            }
        }
    }
}

// layer-1 gemm (2D grid, plain)
__global__ __launch_bounds__(256) void gemm_mfma_kernel(
    const ushort_t* __restrict__ Xh, const ushort_t* __restrict__ Xl,
    const ushort_t* __restrict__ Wfh, const ushort_t* __restrict__ Wfl,
    int lw,
    const float* __restrict__ b0, const float* __restrict__ b1,
    const float* __restrict__ b2, const float* __restrict__ b3,
    char* __restrict__ Oq, char* __restrict__ Okv,
    ushort_t* __restrict__ Os) {
    gemm_body(blockIdx.x, blockIdx.y, Xh, Xl, Wfh, Wfl, lw, b0, b1, b2, b3, Oq, Okv, Os);
}

// layer-0 gemm fused with ATOMIC-FREE edge scatter
constexpr int G0B = 196 * 4;

__global__ __launch_bounds__(256) void gemm0_scatter_kernel(
    const ushort_t* __restrict__ Xh, const ushort_t* __restrict__ Xl,
    const ushort_t* __restrict__ Wfh, const ushort_t* __restrict__ Wfl,
    const float* __restrict__ b0, const float* __restrict__ b1,
    const float* __restrict__ b2, const float* __restrict__ b3,
    char* __restrict__ Oq, char* __restrict__ Okv, ushort_t* __restrict__ Os,
    const int* __restrict__ src, const int* __restrict__ dst,
    const int* __restrict__ offsets, const int* __restrict__ rank,
    int* __restrict__ sorted_src) {
    int b = blockIdx.x;
    if (b >= G0B) {
        int e = (b - G0B) * 256 + threadIdx.x;
        if (e < Ee) sorted_src[offsets[dst[e]] + rank[e]] = src[e];
        return;
    }
    gemm_body(b % 196, b / 196, Xh, Xl, Wfh, Wfl, 0, b0, b1, b2, b3, Oq, Okv, Os);
}

// ---------------- fused per-node attention (int8 q.k dot, fp8 v) ------------
// R11 structure; k-path now 4 sdot4 on raw words (no decode), alpha =
// int_dot * SCALE/256. 8 groups x 8 lanes; lane owns dims [gl*16,+16);
// each edge reads one contiguous 256B kv block [k_int8|v_fp8].

__global__ __launch_bounds__(256) void attn_kernel(const char* __restrict__ q,
                                                   const char* __restrict__ kv,
                                                   const ushort_t* __restrict__ s,
                                                   const int* __restrict__ offsets,
                                                   const int* __restrict__ sorted_src,
                                                   ushort_t* __restrict__ oh,
                                                   ushort_t* __restrict__ ol,
                                                   int write_split) {
    int wid = blockIdx.x * 4 + (threadIdx.x >> 6);
    if (wid >= Nn) return;
    int lane = threadIdx.x & 63;
    int g = lane >> 3;           // edge parity group 0..7
    int gl = lane & 7;           // dim chunk: [gl*16, gl*16+16)
    int4 qw = *(const int4*)(q + (size_t)wid * 128 + gl * 16);   // 16 int8 dims
    int beg = offsets[wid], end = offsets[wid + 1];

    float l = 0.f;
    float acc[16];
#pragma unroll
    for (int j = 0; j < 16; ++j) acc[j] = 0.f;

    for (int e = beg + g; e < end; e += 8) {
        int sidx = sorted_src[e];
        const char* kvp = kv + (size_t)sidx * 256 + gl * 16;
        int4 kw = *(const int4*)(kvp);
        int4 vw = *(const int4*)(kvp + 128);
        int di = __builtin_amdgcn_sdot4(qw.x, kw.x, 0, false);
        di = __builtin_amdgcn_sdot4(qw.y, kw.y, di, false);
        di = __builtin_amdgcn_sdot4(qw.z, kw.z, di, false);
        di = __builtin_amdgcn_sdot4(qw.w, kw.w, di, false);
        di += __shfl_xor(di, 1, 64);
        di += __shfl_xor(di, 2, 64);
        di += __shfl_xor(di, 4, 64);
        float pw = __expf((float)di * ISC);
        l += pw;
        float vf[16];
        fp8x4_to_f32(vw.x, vf);      fp8x4_to_f32(vw.y, vf + 4);
        fp8x4_to_f32(vw.z, vf + 8);  fp8x4_to_f32(vw.w, vf + 12);
#pragma unroll
        for (int j = 0; j < 16; ++j) acc[j] += pw * vf[j];
    }

    // plain-sum merge across the 8 groups (same gl holds same dims)
#pragma unroll
    for (int off = 8; off <= 32; off <<= 1) {
        l += __shfl_xor(l, off, 64);
#pragma unroll
        for (int j = 0; j < 16; ++j) acc[j] += __shfl_xor(acc[j], off, 64);
    }

    if (g == 0) {
        float inv = (l > 0.f) ? (1.0f / l) : 0.f;   // deg==0 -> pure skip
        const ushort_t* sp = s + (size_t)wid * 128 + gl * 16;
        ushort8 sa = *(const ushort8*)(sp);
        ushort8 sb = *(const ushort8*)(sp + 8);
        float ov[16];
#pragma unroll
        for (int j = 0; j < 8; ++j) {
            ov[j]     = fmaxf(acc[j] * inv + bf2f(sa[j]), 0.f);
            ov[j + 8] = fmaxf(acc[j + 8] * inv + bf2f(sb[j]), 0.f);
        }
        if (write_split) {
            ushort8 h0, h1, l0, l1;
#pragma unroll
            for (int j = 0; j < 8; ++j) {
                h0[j] = f2bf(ov[j]);     l0[j] = f2bf(ov[j] - bf2f(h0[j]));
                h1[j] = f2bf(ov[j + 8]); l1[j] = f2bf(ov[j + 8] - bf2f(h1[j]));
            }
            ushort_t* op = oh + (size_t)wid * 128 + gl * 16;
            ushort_t* lp = ol + (size_t)wid * 128 + gl * 16;
            *(ushort8*)(op)     = h0;
            *(ushort8*)(op + 8) = h1;
            *(ushort8*)(lp)     = l0;
            *(ushort8*)(lp + 8) = l1;
        } else {
            ushort8 h0, h1;
#pragma unroll
            for (int j = 0; j < 8; ++j) { h0[j] = f2bf(ov[j]); h1[j] = f2bf(ov[j + 8]); }
            ushort_t* op = oh + (size_t)wid * 128 + gl * 16;
            *(ushort8*)(op)     = h0;
            *(ushort8*)(op + 8) = h1;
        }
    }
}

// ---------------- pooling (bf16 h, coalesced rows, LDS partials) ----------------

__global__ __launch_bounds__(256) void pool_kernel(const ushort_t* __restrict__ hb,
                                                   const int* __restrict__ batch,
                                                   float* __restrict__ pooled) {
    __shared__ float ps[4][128];
    int n0 = blockIdx.x * 256;
    int t = threadIdx.x;
    int lane32 = t & 31, rowgrp = t >> 5;
    for (int i = t; i < 512; i += 256) ((float*)ps)[i] = 0.f;
    __syncthreads();
    int gfirst = batch[min(n0, Nn - 1)];
    int d0 = lane32 * 4;
    float a0 = 0.f, a1 = 0.f, a2 = 0.f, a3 = 0.f;
    int curg = -1;
    for (int rr = 0; rr < 32; ++rr) {
        int n = n0 + rowgrp + rr * 8;
        if (n >= Nn) break;
        int g = batch[n];
        if (g != curg) {
            if (curg >= 0) {
                int slot = curg - gfirst;
                if (slot < 4) {
                    atomicAdd(&ps[slot][d0],     a0);
                    atomicAdd(&ps[slot][d0 + 1], a1);
                    atomicAdd(&ps[slot][d0 + 2], a2);
                    atomicAdd(&ps[slot][d0 + 3], a3);
                } else {
                    atomicAdd(&pooled[curg * Dd + d0],     a0);
                    atomicAdd(&pooled[curg * Dd + d0 + 1], a1);
                    atomicAdd(&pooled[curg * Dd + d0 + 2], a2);
                    atomicAdd(&pooled[curg * Dd + d0 + 3], a3);
                }
                a0 = a1 = a2 = a3 = 0.f;
            }
            curg = g;
        }
        ushort4 hv = *(const ushort4*)(hb + (size_t)n * 128 + d0);
        a0 += bf2f(hv.x); a1 += bf2f(hv.y); a2 += bf2f(hv.z); a3 += bf2f(hv.w);
    }
    if (curg >= 0) {
        int slot = curg - gfirst;
        if (slot < 4) {
            atomicAdd(&ps[slot][d0],     a0);
            atomicAdd(&ps[slot][d0 + 1], a1);
            atomicAdd(&ps[slot][d0 + 2], a2);
            atomicAdd(&ps[slot][d0 + 3], a3);
        } else {
            atomicAdd(&pooled[curg * Dd + d0],     a0);
            atomicAdd(&pooled[curg * Dd + d0 + 1], a1);
            atomicAdd(&pooled[curg * Dd + d0 + 2], a2);
            atomicAdd(&pooled[curg * Dd + d0 + 3], a3);
        }
    }
    __syncthreads();
    int glast = batch[min(n0 + 255, Nn - 1)];
    int nslots = min(glast - gfirst + 1, 4);
    for (int i = t; i < nslots * 128; i += 256) {
        int slot = i >> 7, d = i & 127;
        atomicAdd(&pooled[(gfirst + slot) * Dd + d], ps[slot][d]);
    }
}

__global__ __launch_bounds__(64) void mlp_kernel(const float* __restrict__ pooled,
                                                 const int* __restrict__ startg,
                                                 const int* __restrict__ endg,
                                                 const float* __restrict__ Wc1,
                                                 const float* __restrict__ bc1,
                                                 const float* __restrict__ Wc2,
                                                 const float* __restrict__ bc2,
                                                 float* __restrict__ out) {
    __shared__ float pm[128];
    __shared__ float hid[64];
    int g = blockIdx.x, t = threadIdx.x;   // 64 threads
    float cnt = fmaxf((float)(endg[g] - startg[g]), 1.0f);
    float invc = 1.0f / cnt;
    pm[t]      = pooled[g * 128 + t] * invc;
    pm[t + 64] = pooled[g * 128 + 64 + t] * invc;
    __syncthreads();
    float acc = bc1[t];
    for (int i = 0; i < 128; ++i) acc += pm[i] * Wc1[t * 128 + i];
    hid[t] = fmaxf(acc, 0.f);
    __syncthreads();
    if (t < 2) {
        float a = bc2[t];
        for (int i = 0; i < 64; ++i) a += hid[i] * Wc2[t * 64 + i];
        out[g * 2 + t] = a;
    }
}

// ---------------- launch ----------------

extern "C" void kernel_launch(void* const* d_in, const int* in_sizes, int n_in,
                              void* d_out, int out_size, void* d_ws, size_t ws_size,
                              hipStream_t stream) {
    const float* x   = (const float*)d_in[0];
    const int*   ei  = (const int*)d_in[1];
    const int* batch = (const int*)d_in[2];
    const float* W[2][4];
    const float* B[2][4];
    for (int l = 0; l < 2; ++l) {
        for (int j = 0; j < 4; ++j) W[l][j] = (const float*)d_in[3 + l * 8 + j];
        for (int j = 0; j < 4; ++j) B[l][j] = (const float*)d_in[3 + l * 8 + 4 + j];
    }
    const float* Wc1 = (const float*)d_in[19];
    const float* bc1 = (const float*)d_in[20];
    const float* Wc2 = (const float*)d_in[21];
    const float* bc2 = (const float*)d_in[22];
    float* out = (float*)d_out;

    const int* src = ei;        // edge_index[0]
    const int* dst = ei + Ee;   // edge_index[1]

    char* p = (char*)d_ws;
    auto alloc = [&](size_t bytes) {
        void* r = (void*)p;
        p += (bytes + 255) & ~(size_t)255;
        return r;
    };
    char*     q  = (char*)alloc((size_t)Nn * 128);          // int8 (scale 16)
    char*     kv = (char*)alloc((size_t)Nn * 256);          // [k_int8|v_fp8]
    ushort_t* ss = (ushort_t*)alloc((size_t)Nn * 128 * 2);  // bf16
    ushort_t* hb = (ushort_t*)alloc((size_t)Nn * 128 * 2);  // bf16 layer-2 h
    ushort_t* Xh = (ushort_t*)alloc((size_t)Nn * 128 * 2);
    ushort_t* Xl = (ushort_t*)alloc((size_t)Nn * 128 * 2);
    ushort_t* Wfh = (ushort_t*)alloc((size_t)8 * 16384 * 2);
    ushort_t* Wfl = (ushort_t*)alloc((size_t)8 * 16384 * 2);
    char* zbase = p;  // region zeroed each launch
    int*   counts = (int*)alloc(Nn * 4);
    int*   startg = (int*)alloc(Gg * 4);
    int*   endg   = (int*)alloc(Gg * 4);
    float* pooled = (float*)alloc(Gg * Dd * 4);
    size_t zbytes = (size_t)(p - zbase);
    int* offsets    = (int*)alloc((size_t)(Nn + 1) * 4);
    int* rank       = (int*)alloc((size_t)Ee * 4);
    int* blockSums  = (int*)alloc(256 * 4);
    int* sorted_src = (int*)alloc((size_t)Ee * 4);

    hipMemsetAsync(zbase, 0, zbytes, stream);

    constexpr int NB = (Nn + 255) / 256;  // 196 scan blocks

    // prep: hist(+rank) + bounds + convw + convx (independent, one launch)
    prep_kernel<<<EB + NBD + CWB + CXB, 256, 0, stream>>>(
        dst, counts, rank, batch, startg, endg,
        W[0][0], W[0][1], W[0][2], W[0][3], W[1][0], W[1][1], W[1][2], W[1][3],
        Wfh, Wfl, x, Xh, Xl);
    scan1_kernel<<<NB, 256, 0, stream>>>(counts, offsets, blockSums);
    scan2_kernel<<<1, 256, 0, stream>>>(blockSums, NB);
    scan3_kernel<<<NB, 256, 0, stream>>>(offsets, blockSums);

    // layer-0 gemm fused with atomic-free scatter
    gemm0_scatter_kernel<<<G0B + EB, 256, 0, stream>>>(
        Xh, Xl, Wfh, Wfl, B[0][0], B[0][1], B[0][2], B[0][3],
        q, kv, ss, src, dst, offsets, rank, sorted_src);

    // layer-0 attn writes split-bf16 h straight into Xh/Xl
    attn_kernel<<<(Nn + 3) / 4, 256, 0, stream>>>(q, kv, ss, offsets, sorted_src,
                                                  Xh, Xl, 1);
    // layer 1
    dim3 ggrid(196, 4);
    gemm_mfma_kernel<<<ggrid, 256, 0, stream>>>(Xh, Xl, Wfh, Wfl, 4,
                                                B[1][0], B[1][1], B[1][2], B[1][3],
                                                q, kv, ss);
    attn_kernel<<<(Nn + 3) / 4, 256, 0, stream>>>(q, kv, ss, offsets, sorted_src,
                                                  hb, hb, 0);

    pool_kernel<<<(Nn + 255) / 256, 256, 0, stream>>>(hb, batch, pooled);
    mlp_kernel<<<Gg, 64, 0, stream>>>(pooled, startg, endg, Wc1, bc1, Wc2, bc2, out);
}